// Round 6
// baseline (51206.232 us; speedup 1.0000x reference)
//
#include <hip/hip_runtime.h>
#include <hip/hip_bf16.h>

__device__ __forceinline__ float fast_exp2(float x){
#if __has_builtin(__builtin_amdgcn_exp2f)
  return __builtin_amdgcn_exp2f(x);
#else
  return exp2f(x);
#endif
}
__device__ __forceinline__ float fast_rcp(float x){
#if __has_builtin(__builtin_amdgcn_rcpf)
  return __builtin_amdgcn_rcpf(x);
#else
  return 1.0f/x;
#endif
}

typedef float v2f __attribute__((ext_vector_type(2)));
typedef float v4f __attribute__((ext_vector_type(4)));

// quad_perm DPP: 0xB1 = [1,0,3,2] (xor1), 0x4E = [2,3,0,1] (xor2), 0x1B = xor3
template<int CTRL>
__device__ __forceinline__ float qperm(float v){
  return __int_as_float(__builtin_amdgcn_update_dpp(0, __float_as_int(v), CTRL, 0xF, 0xF, true));
}
// sum over the 4 lanes of a quad, result in every lane (verified primitive)
__device__ __forceinline__ float quad_sum(float v){
  v += qperm<0xB1>(v);
  v += qperm<0x4E>(v);
  return v;
}

// LDS-only barrier: do NOT drain vmcnt (DMA loads / hs stores stay in flight).
#define LDS_BARRIER() __asm__ __volatile__("s_waitcnt lgkmcnt(0)\n\ts_barrier" ::: "memory")
// Block-boundary barrier: additionally retire the 2 oldest VMEM ops per wave
// (the xp DMA loads for the next block), leaving the 8 hs stores in flight.
#define VM_LDS_BARRIER() __asm__ __volatile__("s_waitcnt vmcnt(8) lgkmcnt(0)\n\ts_barrier" ::: "memory")

// Force the 8 v2f weight pairs of one gate to live in VGPRs at this point.
#define PIN8(a) __asm__ __volatile__("" : "+v"((a)[0]), "+v"((a)[1]), "+v"((a)[2]), \
    "+v"((a)[3]), "+v"((a)[4]), "+v"((a)[5]), "+v"((a)[6]), "+v"((a)[7]))

#define LOG2E 1.442695040888963f

// xproj lane->row mapping: tid=(w,l): row = (l&3)*64 + w*16 + (l>>2).
// => float4 at unit u = w*16+(l>>2) holds (zi,zf,zg,zo).
__global__ __launch_bounds__(256) void xproj_kernel(
    const float* __restrict__ x, const float* __restrict__ W_ih,
    const float* __restrict__ b_ih, const float* __restrict__ b_hh,
    float* __restrict__ xp, int T)
{
  const int tid = threadIdx.x;
  const int w = tid >> 6, l = tid & 63;
  const int row = (l & 3) * 64 + w * 16 + (l >> 2);
  float wv[64];
  {
    const float4* wr = (const float4*)(W_ih + (size_t)row*64);
    #pragma unroll
    for (int k=0;k<16;++k){ float4 q = wr[k]; wv[4*k]=q.x; wv[4*k+1]=q.y; wv[4*k+2]=q.z; wv[4*k+3]=q.w; }
  }
  const float bias = b_ih[row] + b_hh[row];
  __shared__ alignas(16) float xs[8][64];
  const int t0 = blockIdx.x * 128;
  for (int tt=0; tt<128; tt+=8){
    __syncthreads();
    xs[tid>>6][tid&63] = x[(size_t)(t0+tt)*64 + tid];
    const int f2i = tid + 256;
    xs[f2i>>6][f2i&63] = x[(size_t)(t0+tt)*64 + f2i];
    __syncthreads();
    #pragma unroll
    for (int j=0;j<8;++j){
      const float4* xr = (const float4*)xs[j];
      float a0=0,a1=0,a2=0,a3=0;
      #pragma unroll
      for (int k=0;k<16;++k){
        float4 q = xr[k];
        a0 = fmaf(wv[4*k+0], q.x, a0);
        a1 = fmaf(wv[4*k+1], q.y, a1);
        a2 = fmaf(wv[4*k+2], q.z, a2);
        a3 = fmaf(wv[4*k+3], q.w, a3);
      }
      xp[(size_t)(t0+tt+j)*256 + tid] = bias + ((a0+a1)+(a2+a3));
    }
  }
}

// ---- MODE 0 fast path: quad-local k-split-4 scan, xp via LDS-DMA ----------
// 256 threads. lane (w,l): slice s=l&3, unit u=w*16+(l>>2).
// Weights as v2f pairs (even/odd k) -> v_pk_fma_f32; pinned to VGPRs per
// block via empty asm with "v" constraints (defeats AGPR/scratch shuttling).
__global__ __launch_bounds__(256,1) void lstm_scan_q4(
    const float* __restrict__ xp, const float* __restrict__ W_hh,
    float* __restrict__ hs, int T)
{
  const int tid = threadIdx.x;
  const int w = tid >> 6, l = tid & 63;
  const int s = l & 3;
  const int u = w * 16 + (l >> 2);

  // wgX[j] = {W[row][16s+2j], W[row][16s+2j+1]}, j in [0,8)
  v2f wgI[8], wgF[8], wgG[8], wgO[8];
  {
    const v4f* wrI = (const v4f*)(W_hh + (size_t)(      u)*64 + s*16);
    const v4f* wrF = (const v4f*)(W_hh + (size_t)( 64 + u)*64 + s*16);
    const v4f* wrG = (const v4f*)(W_hh + (size_t)(128 + u)*64 + s*16);
    const v4f* wrO = (const v4f*)(W_hh + (size_t)(192 + u)*64 + s*16);
    #pragma unroll
    for (int q=0; q<4; ++q){
      v4f a = wrI[q]; wgI[2*q] = __builtin_shufflevector(a,a,0,1); wgI[2*q+1] = __builtin_shufflevector(a,a,2,3);
      v4f b = wrF[q]; wgF[2*q] = __builtin_shufflevector(b,b,0,1); wgF[2*q+1] = __builtin_shufflevector(b,b,2,3);
      v4f c2= wrG[q]; wgG[2*q] = __builtin_shufflevector(c2,c2,0,1); wgG[2*q+1] = __builtin_shufflevector(c2,c2,2,3);
      v4f d = wrO[q]; wgO[2*q] = __builtin_shufflevector(d,d,0,1); wgO[2*q+1] = __builtin_shufflevector(d,d,2,3);
    }
  }

  __shared__ alignas(16) float hb[2][64];
  __shared__ alignas(16) float xbuf[2][2048];   // 2 x (8 steps x 256 floats)
  if (tid < 64){ hb[0][tid] = 0.f; hb[1][tid] = 0.f; }

  // DMA: block blk (8 steps of xp, 2048 floats) -> xbuf[buf], linear layout.
  auto issue_dma = [&](int buf, int blk){
    #pragma unroll
    for (int r=0;r<2;++r){
      const float* g = xp + (size_t)blk*2048 + (size_t)(w*2+r)*256 + l*4;
      float* ld = &xbuf[buf][(w*2+r)*256];
      __builtin_amdgcn_global_load_lds(
          (const __attribute__((address_space(1))) void*)g,
          (__attribute__((address_space(3))) void*)ld, 16, 0, 0);
    }
  };

  float c = 0.f;
  float* hsu = hs + u;

  issue_dma(0, 0);
  __asm__ __volatile__("s_waitcnt vmcnt(0)" ::: "memory");
  __syncthreads();

  const int NB = T >> 3;
  for (int bi = 0; bi < NB; ++bi){
    const int p = bi & 1;
    if (bi + 1 < NB) issue_dma(p^1, bi+1);   // oldest VMEM ops of this block
    PIN8(wgI); PIN8(wgF); PIN8(wgG); PIN8(wgO);   // keep weights VGPR-resident
    #pragma unroll
    for (int j=0;j<8;++j){
      const int t = (bi<<3) + j;
      const v4f xv = *(const v4f*)&xbuf[p][j*256 + u*4];     // quad-broadcast
      const v4f* hp = (const v4f*)(&hb[t&1][s*16]);
      v2f aI = {0.f,0.f}, aF = {0.f,0.f}, aG = {0.f,0.f}, aO = {0.f,0.f};
      #pragma unroll
      for (int m=0;m<4;++m){
        v4f h4 = hp[m];
        v2f h01 = __builtin_shufflevector(h4,h4,0,1);
        v2f h23 = __builtin_shufflevector(h4,h4,2,3);
        aI = aI + wgI[2*m]*h01;  aI = aI + wgI[2*m+1]*h23;
        aF = aF + wgF[2*m]*h01;  aF = aF + wgF[2*m+1]*h23;
        aG = aG + wgG[2*m]*h01;  aG = aG + wgG[2*m+1]*h23;
        aO = aO + wgO[2*m]*h01;  aO = aO + wgO[2*m+1]*h23;
      }
      // reduce across the 4 slices of this quad (DPP, verified)
      const float zi = quad_sum(aI.x + aI.y) + xv.x;
      const float zf = quad_sum(aF.x + aF.y) + xv.y;
      const float zg = quad_sum(aG.x + aG.y) + xv.z;
      const float zo = quad_sum(aO.x + aO.y) + xv.w;
      const float i_ = fast_rcp(1.f + fast_exp2(-LOG2E * zi));
      const float f_ = fast_rcp(1.f + fast_exp2(-LOG2E * zf));
      const float o_ = fast_rcp(1.f + fast_exp2(-LOG2E * zo));
      const float g_ = fmaf(fast_rcp(1.f + fast_exp2(-2.f*LOG2E * zg)), 2.f, -1.f);
      c = fmaf(f_, c, i_ * g_);
      const float tc = fmaf(fast_rcp(1.f + fast_exp2(-2.f*LOG2E * c)), 2.f, -1.f);
      const float h = o_ * tc;
      if (s == 0){
        hb[(t&1)^1][u] = h;
        hsu[(size_t)t*64] = h;
      }
      if (j == 7) { VM_LDS_BARRIER(); }
      else        { LDS_BARRIER(); }
    }
  }
}

// ---- fallback scan (MODES 1,2) — round-2-verified structure ----------------
template<int MODE>
__global__ __launch_bounds__(256,1) void lstm_scan(
    const float* __restrict__ xp, const float* __restrict__ x,
    const float* __restrict__ W_ih, const float* __restrict__ W_hh,
    const float* __restrict__ b_ih, const float* __restrict__ b_hh,
    const float* __restrict__ W_lin, const float* __restrict__ b_lin,
    const float* __restrict__ W_fin, const float* __restrict__ b_fin,
    float* __restrict__ hs, float* __restrict__ out, int T)
{
  const int tid = threadIdx.x;
  const int w = tid >> 6, l = tid & 63;
  const int gate = l & 3;
  const int u64i = w * 16 + (l >> 2);
  const int row = gate * 64 + u64i;

  float wv[64];
  { const float4* wr = (const float4*)(W_hh + (size_t)row*64);
    #pragma unroll
    for (int k=0;k<16;++k){ float4 q=wr[k]; wv[4*k]=q.x; wv[4*k+1]=q.y; wv[4*k+2]=q.z; wv[4*k+3]=q.w; } }

  const bool isg = (gate == 2);
  const float kscale = isg ? (-2.f*LOG2E) : (-LOG2E);
  const float kmul = isg ? 2.f : 1.f;
  const float kadd = isg ? -1.f : 0.f;
  float c = 0.f;

  __shared__ alignas(16) float hbufs[2][64];
  if (tid < 64){ hbufs[0][tid] = 0.f; hbufs[1][tid] = 0.f; }

  float wih[64]; float bias = 0.f;
  __shared__ alignas(16) float xlds[2][512];
  float px0=0.f, px1=0.f;
  const size_t N = (size_t)T * 64;

  {
    const float4* wr = (const float4*)(W_ih + (size_t)row*64);
    #pragma unroll
    for (int k=0;k<16;++k){ float4 q=wr[k]; wih[4*k]=q.x; wih[4*k+1]=q.y; wih[4*k+2]=q.z; wih[4*k+3]=q.w; }
    bias = b_ih[row] + b_hh[row];
    px0 = x[tid]; px1 = x[(size_t)tid + 256];
    xlds[0][tid] = px0; xlds[0][tid+256] = px1;
    size_t i0 = (size_t)512 + tid, i1 = (size_t)512 + tid + 256;
    px0 = x[i0 < N ? i0 : (N-1)];
    px1 = x[i1 < N ? i1 : (N-1)];
  }

  float wlin[64], blin_l=0.f, wfin_l=0.f, bfin=0.f;
  if (MODE == 2){
    const float4* wr = (const float4*)(W_lin + (size_t)l*64);
    #pragma unroll
    for (int k=0;k<16;++k){ float4 q=wr[k]; wlin[4*k]=q.x; wlin[4*k+1]=q.y; wlin[4*k+2]=q.z; wlin[4*k+3]=q.w; }
    blin_l = b_lin[l]; wfin_l = W_fin[l]; bfin = b_fin[0];
  }

  __syncthreads();

  for (int tb = 0; tb < T; tb += 8){
    {
      const int gi = tb >> 3;
      float* xd = xlds[(gi+1)&1];
      xd[tid] = px0; xd[tid+256] = px1;
      const size_t base = (size_t)(gi+2) * 512;
      size_t i0 = base + tid, i1 = base + tid + 256;
      px0 = x[i0 < N ? i0 : (N-1)];
      px1 = x[i1 < N ? i1 : (N-1)];
    }
    #pragma unroll
    for (int j=0;j<8;++j){
      const int t = tb + j;
      const float4* hbp = (const float4*)hbufs[t&1];
      float a0=0,a1=0,a2=0,a3=0;
      float m0=0,m1=0,m2=0,m3=0;
      #pragma unroll
      for (int k=0;k<16;++k){
        float4 hk = hbp[k];
        a0 = fmaf(wv[4*k+0], hk.x, a0);
        a1 = fmaf(wv[4*k+1], hk.y, a1);
        a2 = fmaf(wv[4*k+2], hk.z, a2);
        a3 = fmaf(wv[4*k+3], hk.w, a3);
        if (MODE == 2){
          m0 = fmaf(wlin[4*k+0], fmaxf(hk.x,0.f), m0);
          m1 = fmaf(wlin[4*k+1], fmaxf(hk.y,0.f), m1);
          m2 = fmaf(wlin[4*k+2], fmaxf(hk.z,0.f), m2);
          m3 = fmaf(wlin[4*k+3], fmaxf(hk.w,0.f), m3);
        }
      }
      float z = (a0+a1)+(a2+a3);
      {
        const float4* xr = (const float4*)&xlds[(tb>>3)&1][j*64];
        float b0=0,b1=0,b2=0,b3=0;
        #pragma unroll
        for (int k=0;k<16;++k){
          float4 q = xr[k];
          b0 = fmaf(wih[4*k+0], q.x, b0);
          b1 = fmaf(wih[4*k+1], q.y, b1);
          b2 = fmaf(wih[4*k+2], q.z, b2);
          b3 = fmaf(wih[4*k+3], q.w, b3);
        }
        z += bias + ((b0+b1)+(b2+b3));
      }
      if (MODE == 2){
        float mid = fmaxf(blin_l + ((m0+m1)+(m2+m3)), 0.f);
        float po = wfin_l * mid;
        if (w == 0){
          po += __shfl_xor(po,1); po += __shfl_xor(po,2); po += __shfl_xor(po,4);
          po += __shfl_xor(po,8); po += __shfl_xor(po,16); po += __shfl_xor(po,32);
          if (l == 0 && t > 0) out[t-1] = po + bfin;
        }
      }
      float e = fast_exp2(z * kscale);
      float sgm = fast_rcp(1.f + e);
      float v = fmaf(sgm, kmul, kadd);
      const float q1 = qperm<0xB1>(v);
      const float q2 = qperm<0x4E>(v);
      const float q3 = qperm<0x1B>(v);
      c = fmaf(q1, c, v * q2);
      const float e2 = fast_exp2((-2.f*LOG2E) * c);
      const float tc = fmaf(fast_rcp(1.f + e2), 2.f, -1.f);
      const float h = q3 * tc;
      if ((l & 3) == 0){
        hbufs[(t&1)^1][u64i] = h;
        if (MODE <= 1) hs[(size_t)t*64 + u64i] = h;
      }
      LDS_BARRIER();
    }
  }
  if (MODE == 2){
    const float4* hbp = (const float4*)hbufs[T&1];
    float m0=0,m1=0,m2=0,m3=0;
    #pragma unroll
    for (int k=0;k<16;++k){
      float4 hk = hbp[k];
      m0 = fmaf(wlin[4*k+0], fmaxf(hk.x,0.f), m0);
      m1 = fmaf(wlin[4*k+1], fmaxf(hk.y,0.f), m1);
      m2 = fmaf(wlin[4*k+2], fmaxf(hk.z,0.f), m2);
      m3 = fmaf(wlin[4*k+3], fmaxf(hk.w,0.f), m3);
    }
    float mid = fmaxf(blin_l + ((m0+m1)+(m2+m3)), 0.f);
    float po = wfin_l * mid;
    if (w == 0){
      po += __shfl_xor(po,1); po += __shfl_xor(po,2); po += __shfl_xor(po,4);
      po += __shfl_xor(po,8); po += __shfl_xor(po,16); po += __shfl_xor(po,32);
      if (l == 0) out[T-1] = po + bfin;
    }
  }
}

__global__ __launch_bounds__(128) void postproc_kernel(
    const float* __restrict__ hs, const float* __restrict__ W_lin,
    const float* __restrict__ b_lin, const float* __restrict__ W_fin,
    const float* __restrict__ b_fin, float* __restrict__ out, int T)
{
  __shared__ alignas(16) float wl[4096];
  __shared__ float ht[128][65];
  __shared__ float sb[64], sw[64];
  const int tid = threadIdx.x;
  #pragma unroll
  for (int i=0;i<32;++i){ int f = tid + i*128; wl[f] = W_lin[f]; }
  if (tid < 64){ sb[tid] = b_lin[tid]; sw[tid] = W_fin[tid]; }
  const size_t t0 = (size_t)blockIdx.x * 128;
  #pragma unroll
  for (int i=0;i<64;++i){ int f = tid + i*128; ht[f>>6][f&63] = hs[t0*64 + f]; }
  __syncthreads();
  float rh[64];
  #pragma unroll
  for (int k=0;k<64;++k) rh[k] = fmaxf(ht[tid][k], 0.f);
  float acc = b_fin[0];
  for (int j=0;j<64;++j){
    const float4* wr = (const float4*)(wl + j*64);
    float m0=sb[j],m1=0,m2=0,m3=0;
    #pragma unroll
    for (int k=0;k<16;++k){
      float4 q = wr[k];
      m0 = fmaf(q.x, rh[4*k+0], m0);
      m1 = fmaf(q.y, rh[4*k+1], m1);
      m2 = fmaf(q.z, rh[4*k+2], m2);
      m3 = fmaf(q.w, rh[4*k+3], m3);
    }
    acc = fmaf(sw[j], fmaxf((m0+m1)+(m2+m3), 0.f), acc);
  }
  out[t0 + tid] = acc;
}

extern "C" void kernel_launch(void* const* d_in, const int* in_sizes, int n_in,
                              void* d_out, int out_size, void* d_ws, size_t ws_size,
                              hipStream_t stream)
{
  const float* x    = (const float*)d_in[0];
  const float* W_ih = (const float*)d_in[1];
  const float* W_hh = (const float*)d_in[2];
  const float* b_ih = (const float*)d_in[3];
  const float* b_hh = (const float*)d_in[4];
  const float* W_lin= (const float*)d_in[5];
  const float* b_lin= (const float*)d_in[6];
  const float* W_fin= (const float*)d_in[7];
  const float* b_fin= (const float*)d_in[8];
  float* out = (float*)d_out;
  const int T = in_sizes[0] / 64;
  const size_t xp_bytes = (size_t)T * 256 * sizeof(float);
  const size_t hs_bytes = (size_t)T * 64 * sizeof(float);

  if (ws_size >= xp_bytes + hs_bytes){
    float* xp = (float*)d_ws;
    float* hs = (float*)((char*)d_ws + xp_bytes);
    xproj_kernel<<<T/128, 256, 0, stream>>>(x, W_ih, b_ih, b_hh, xp, T);
    lstm_scan_q4<<<1, 256, 0, stream>>>(xp, W_hh, hs, T);
    postproc_kernel<<<T/128, 128, 0, stream>>>(hs, W_lin, b_lin, W_fin, b_fin, out, T);
  } else if (ws_size >= hs_bytes){
    float* hs = (float*)d_ws;
    lstm_scan<1><<<1, 256, 0, stream>>>(nullptr, x, W_ih, W_hh, b_ih, b_hh,
                                        W_lin, b_lin, W_fin, b_fin, hs, out, T);
    postproc_kernel<<<T/128, 128, 0, stream>>>(hs, W_lin, b_lin, W_fin, b_fin, out, T);
  } else {
    lstm_scan<2><<<1, 256, 0, stream>>>(nullptr, x, W_ih, W_hh, b_ih, b_hh,
                                        W_lin, b_lin, W_fin, b_fin, nullptr, out, T);
  }
}

// Round 8
// 36632.812 us; speedup vs baseline: 1.3978x; 1.3978x over previous
//
#include <hip/hip_runtime.h>
#include <hip/hip_bf16.h>

__device__ __forceinline__ float fast_exp2(float x){
#if __has_builtin(__builtin_amdgcn_exp2f)
  return __builtin_amdgcn_exp2f(x);
#else
  return exp2f(x);
#endif
}
__device__ __forceinline__ float fast_rcp(float x){
#if __has_builtin(__builtin_amdgcn_rcpf)
  return __builtin_amdgcn_rcpf(x);
#else
  return 1.0f/x;
#endif
}

template<int CTRL>
__device__ __forceinline__ float qperm(float v){
  return __int_as_float(__builtin_amdgcn_update_dpp(0, __float_as_int(v), CTRL, 0xF, 0xF, true));
}

#define LDS_BARRIER() __asm__ __volatile__("s_waitcnt lgkmcnt(0)\n\ts_barrier" ::: "memory")
#define LOG2E 1.442695040888963f

// xproj lane->row mapping: tid=(w,l): row = (l&3)*64 + w*16 + (l>>2).
// => float4 at unit u = w*16+(l>>2) holds (zi,zf,zg,zo).
__global__ __launch_bounds__(256) void xproj_kernel(
    const float* __restrict__ x, const float* __restrict__ W_ih,
    const float* __restrict__ b_ih, const float* __restrict__ b_hh,
    float* __restrict__ xp, int T)
{
  const int tid = threadIdx.x;
  const int w = tid >> 6, l = tid & 63;
  const int row = (l & 3) * 64 + w * 16 + (l >> 2);
  float wv[64];
  {
    const float4* wr = (const float4*)(W_ih + (size_t)row*64);
    #pragma unroll
    for (int k=0;k<16;++k){ float4 q = wr[k]; wv[4*k]=q.x; wv[4*k+1]=q.y; wv[4*k+2]=q.z; wv[4*k+3]=q.w; }
  }
  const float bias = b_ih[row] + b_hh[row];
  __shared__ alignas(16) float xs[8][64];
  const int t0 = blockIdx.x * 128;
  for (int tt=0; tt<128; tt+=8){
    __syncthreads();
    xs[tid>>6][tid&63] = x[(size_t)(t0+tt)*64 + tid];
    const int f2i = tid + 256;
    xs[f2i>>6][f2i&63] = x[(size_t)(t0+tt)*64 + f2i];
    __syncthreads();
    #pragma unroll
    for (int j=0;j<8;++j){
      const float4* xr = (const float4*)xs[j];
      float a0=0,a1=0,a2=0,a3=0;
      #pragma unroll
      for (int k=0;k<16;++k){
        float4 q = xr[k];
        a0 = fmaf(wv[4*k+0], q.x, a0);
        a1 = fmaf(wv[4*k+1], q.y, a1);
        a2 = fmaf(wv[4*k+2], q.z, a2);
        a3 = fmaf(wv[4*k+3], q.w, a3);
      }
      xp[(size_t)(t0+tt+j)*256 + tid] = bias + ((a0+a1)+(a2+a3));
    }
  }
}

// ===== full inline-asm scan ==================================================
// Register map (fixed, all clobbered):
//  v0 h-read LDS addr (hbase+s*64)   v1 hs voffset (u*4)   v2 h-write addr (hbase+u*4)
//  v3 c    v4-v11 pk accumulators / z    v12-v13 temps
//  v16-v31 h (4x b128)   v32-v95 W_hh quad weights   v96-v159 xp banks A/B
//  v160 xp voffset (u*16)   v161 weight-load offset cursor

#define S_READS(R0,R1,R2,R3) \
  "ds_read_b128 v[16:19], v0 offset:" R0 "\n" \
  "ds_read_b128 v[20:23], v0 offset:" R1 "\n" \
  "ds_read_b128 v[24:27], v0 offset:" R2 "\n" \
  "ds_read_b128 v[28:31], v0 offset:" R3 "\n" \
  "s_waitcnt lgkmcnt(0)\n"

#define S_DOT \
  "v_pk_mul_f32 v[4:5], v[32:33], v[16:17]\n" \
  "v_pk_mul_f32 v[6:7], v[48:49], v[16:17]\n" \
  "v_pk_mul_f32 v[8:9], v[64:65], v[16:17]\n" \
  "v_pk_mul_f32 v[10:11], v[80:81], v[16:17]\n" \
  "v_pk_fma_f32 v[4:5], v[34:35], v[18:19], v[4:5]\n" \
  "v_pk_fma_f32 v[6:7], v[50:51], v[18:19], v[6:7]\n" \
  "v_pk_fma_f32 v[8:9], v[66:67], v[18:19], v[8:9]\n" \
  "v_pk_fma_f32 v[10:11], v[82:83], v[18:19], v[10:11]\n" \
  "v_pk_fma_f32 v[4:5], v[36:37], v[20:21], v[4:5]\n" \
  "v_pk_fma_f32 v[6:7], v[52:53], v[20:21], v[6:7]\n" \
  "v_pk_fma_f32 v[8:9], v[68:69], v[20:21], v[8:9]\n" \
  "v_pk_fma_f32 v[10:11], v[84:85], v[20:21], v[10:11]\n" \
  "v_pk_fma_f32 v[4:5], v[38:39], v[22:23], v[4:5]\n" \
  "v_pk_fma_f32 v[6:7], v[54:55], v[22:23], v[6:7]\n" \
  "v_pk_fma_f32 v[8:9], v[70:71], v[22:23], v[8:9]\n" \
  "v_pk_fma_f32 v[10:11], v[86:87], v[22:23], v[10:11]\n" \
  "v_pk_fma_f32 v[4:5], v[40:41], v[24:25], v[4:5]\n" \
  "v_pk_fma_f32 v[6:7], v[56:57], v[24:25], v[6:7]\n" \
  "v_pk_fma_f32 v[8:9], v[72:73], v[24:25], v[8:9]\n" \
  "v_pk_fma_f32 v[10:11], v[88:89], v[24:25], v[10:11]\n" \
  "v_pk_fma_f32 v[4:5], v[42:43], v[26:27], v[4:5]\n" \
  "v_pk_fma_f32 v[6:7], v[58:59], v[26:27], v[6:7]\n" \
  "v_pk_fma_f32 v[8:9], v[74:75], v[26:27], v[8:9]\n" \
  "v_pk_fma_f32 v[10:11], v[90:91], v[26:27], v[10:11]\n" \
  "v_pk_fma_f32 v[4:5], v[44:45], v[28:29], v[4:5]\n" \
  "v_pk_fma_f32 v[6:7], v[60:61], v[28:29], v[6:7]\n" \
  "v_pk_fma_f32 v[8:9], v[76:77], v[28:29], v[8:9]\n" \
  "v_pk_fma_f32 v[10:11], v[92:93], v[28:29], v[10:11]\n" \
  "v_pk_fma_f32 v[4:5], v[46:47], v[30:31], v[4:5]\n" \
  "v_pk_fma_f32 v[6:7], v[62:63], v[30:31], v[6:7]\n" \
  "v_pk_fma_f32 v[8:9], v[78:79], v[30:31], v[8:9]\n" \
  "v_pk_fma_f32 v[10:11], v[94:95], v[30:31], v[10:11]\n"

// FIXED (R7 bug): quad butterfly FIRST, then add the (quad-uniform) xp term
// once. Adding it before the butterfly counted it 4x.
#define S_REDUCE(X0,X1,X2,X3) \
  "v_add_f32 v4, v4, v5\n" \
  "v_add_f32 v5, v6, v7\n" \
  "v_add_f32 v6, v8, v9\n" \
  "v_add_f32 v7, v10, v11\n" \
  "v_add_f32 v4, v4, v4 quad_perm:[1,0,3,2] row_mask:0xf bank_mask:0xf\n" \
  "v_add_f32 v5, v5, v5 quad_perm:[1,0,3,2] row_mask:0xf bank_mask:0xf\n" \
  "v_add_f32 v6, v6, v6 quad_perm:[1,0,3,2] row_mask:0xf bank_mask:0xf\n" \
  "v_add_f32 v7, v7, v7 quad_perm:[1,0,3,2] row_mask:0xf bank_mask:0xf\n" \
  "v_add_f32 v4, v4, v4 quad_perm:[2,3,0,1] row_mask:0xf bank_mask:0xf\n" \
  "v_add_f32 v5, v5, v5 quad_perm:[2,3,0,1] row_mask:0xf bank_mask:0xf\n" \
  "v_add_f32 v6, v6, v6 quad_perm:[2,3,0,1] row_mask:0xf bank_mask:0xf\n" \
  "v_add_f32 v7, v7, v7 quad_perm:[2,3,0,1] row_mask:0xf bank_mask:0xf\n" \
  "v_add_f32 v4, v4, " X0 "\n" \
  "v_add_f32 v5, v5, " X1 "\n" \
  "v_add_f32 v6, v6, " X2 "\n" \
  "v_add_f32 v7, v7, " X3 "\n"

#define S_NONLIN \
  "v_mul_f32 v8, 0xbfb8aa3b, v4\n" \
  "v_mul_f32 v9, 0xbfb8aa3b, v5\n" \
  "v_mul_f32 v10, 0xc038aa3b, v6\n" \
  "v_mul_f32 v11, 0xbfb8aa3b, v7\n" \
  "v_exp_f32 v8, v8\n" \
  "v_exp_f32 v9, v9\n" \
  "v_exp_f32 v10, v10\n" \
  "v_exp_f32 v11, v11\n" \
  "v_add_f32 v8, 1.0, v8\n" \
  "v_add_f32 v9, 1.0, v9\n" \
  "v_add_f32 v10, 1.0, v10\n" \
  "v_add_f32 v11, 1.0, v11\n" \
  "v_rcp_f32 v8, v8\n" \
  "v_rcp_f32 v9, v9\n" \
  "v_rcp_f32 v10, v10\n" \
  "v_rcp_f32 v11, v11\n" \
  "s_nop 0\n" \
  "v_fma_f32 v10, v10, 2.0, -1.0\n" \
  "v_mul_f32 v12, v8, v10\n" \
  "v_fma_f32 v3, v9, v3, v12\n" \
  "v_mul_f32 v13, 0xc038aa3b, v3\n" \
  "v_exp_f32 v13, v13\n" \
  "s_nop 0\n" \
  "v_add_f32 v13, 1.0, v13\n" \
  "v_rcp_f32 v13, v13\n" \
  "s_nop 0\n" \
  "v_fma_f32 v13, v13, 2.0, -1.0\n" \
  "v_mul_f32 v13, v11, v13\n"

#define S_WRITE_SYNC(WR,SO) \
  "s_and_saveexec_b64 s[12:13], s[10:11]\n" \
  "ds_write_b32 v2, v13 offset:" WR "\n" \
  "global_store_dword v1, v13, s[4:5] offset:" SO "\n" \
  "s_mov_b64 exec, s[12:13]\n" \
  "s_waitcnt lgkmcnt(0)\n" \
  "s_barrier\n"

#define STEP_E(X0,X1,X2,X3,SO) \
  S_READS("0","16","32","48") S_DOT S_REDUCE(X0,X1,X2,X3) S_NONLIN S_WRITE_SYNC("256",SO)
#define STEP_O(X0,X1,X2,X3,SO) \
  S_READS("256","272","288","304") S_DOT S_REDUCE(X0,X1,X2,X3) S_NONLIN S_WRITE_SYNC("0",SO)

#define LOAD_BANK_B \
  "global_load_dwordx4 v[128:131], v160, s[0:1]\n" \
  "global_load_dwordx4 v[132:135], v160, s[0:1] offset:1024\n" \
  "global_load_dwordx4 v[136:139], v160, s[0:1] offset:2048\n" \
  "global_load_dwordx4 v[140:143], v160, s[0:1] offset:3072\n" \
  "global_load_dwordx4 v[144:147], v160, s[2:3]\n" \
  "global_load_dwordx4 v[148:151], v160, s[2:3] offset:1024\n" \
  "global_load_dwordx4 v[152:155], v160, s[2:3] offset:2048\n" \
  "global_load_dwordx4 v[156:159], v160, s[2:3] offset:3072\n"

#define LOAD_BANK_A \
  "global_load_dwordx4 v[96:99], v160, s[0:1]\n" \
  "global_load_dwordx4 v[100:103], v160, s[0:1] offset:1024\n" \
  "global_load_dwordx4 v[104:107], v160, s[0:1] offset:2048\n" \
  "global_load_dwordx4 v[108:111], v160, s[0:1] offset:3072\n" \
  "global_load_dwordx4 v[112:115], v160, s[2:3]\n" \
  "global_load_dwordx4 v[116:119], v160, s[2:3] offset:1024\n" \
  "global_load_dwordx4 v[120:123], v160, s[2:3] offset:2048\n" \
  "global_load_dwordx4 v[124:127], v160, s[2:3] offset:3072\n"

#define ADV_XP \
  "s_add_u32 s0, s0, 0x2000\n" "s_addc_u32 s1, s1, 0\n" \
  "s_add_u32 s2, s2, 0x2000\n" "s_addc_u32 s3, s3, 0\n"

#define ADV_HS \
  "s_add_u32 s4, s4, 0x800\n" "s_addc_u32 s5, s5, 0\n"

__global__ __launch_bounds__(256,1) void lstm_scan_asm(
    const float* __restrict__ xp, const float* __restrict__ W_hh,
    float* __restrict__ hs, int T)
{
  const int tid = threadIdx.x;
  const int w = tid >> 6, l = tid & 63;
  const int s = l & 3;
  const int u = w * 16 + (l >> 2);

  __shared__ alignas(16) float hb[2][64];
  if (tid < 64){ hb[0][tid] = 0.f; hb[1][tid] = 0.f; }
  __syncthreads();

  unsigned hbase = (unsigned)(uintptr_t)(__attribute__((address_space(3))) float*)&hb[0][0];
  unsigned hra = hbase + (unsigned)(s * 64);
  unsigned hwa = hbase + (unsigned)(u * 4);
  unsigned hso = (unsigned)(u * 4);
  unsigned xpo = (unsigned)(u * 16);
  unsigned wof = (unsigned)(u * 256 + s * 64);
  unsigned smk = (s == 0) ? 1u : 0u;
  unsigned long long xpa = (unsigned long long)(uintptr_t)xp;
  unsigned long long hsp = (unsigned long long)(uintptr_t)hs;
  unsigned long long whh = (unsigned long long)(uintptr_t)W_hh;
  int nb2 = T >> 4;

  __asm__ __volatile__(
    // ---- prologue: fixed-reg init ----
    "s_mov_b64 s[0:1], %[xpa]\n"
    "s_add_u32 s2, s0, 0x1000\n"
    "s_addc_u32 s3, s1, 0\n"
    "s_mov_b64 s[4:5], %[hsp]\n"
    "s_mov_b32 s6, %[nb2]\n"
    "s_mov_b64 s[8:9], %[whh]\n"
    "v_mov_b32 v0, %[hra]\n"
    "v_mov_b32 v1, %[hso]\n"
    "v_mov_b32 v2, %[hwa]\n"
    "v_mov_b32 v160, %[xpo]\n"
    "v_mov_b32 v161, %[wof]\n"
    "v_mov_b32 v3, 0\n"
    "v_cmp_eq_u32 vcc, 1, %[smk]\n"
    "s_nop 4\n"
    "s_mov_b64 s[10:11], vcc\n"
    // ---- weights: 4 gates x 4 dwordx4 ----
    "global_load_dwordx4 v[32:35], v161, s[8:9]\n"
    "global_load_dwordx4 v[36:39], v161, s[8:9] offset:16\n"
    "global_load_dwordx4 v[40:43], v161, s[8:9] offset:32\n"
    "global_load_dwordx4 v[44:47], v161, s[8:9] offset:48\n"
    "v_add_u32 v161, 0x4000, v161\n"
    "global_load_dwordx4 v[48:51], v161, s[8:9]\n"
    "global_load_dwordx4 v[52:55], v161, s[8:9] offset:16\n"
    "global_load_dwordx4 v[56:59], v161, s[8:9] offset:32\n"
    "global_load_dwordx4 v[60:63], v161, s[8:9] offset:48\n"
    "v_add_u32 v161, 0x4000, v161\n"
    "global_load_dwordx4 v[64:67], v161, s[8:9]\n"
    "global_load_dwordx4 v[68:71], v161, s[8:9] offset:16\n"
    "global_load_dwordx4 v[72:75], v161, s[8:9] offset:32\n"
    "global_load_dwordx4 v[76:79], v161, s[8:9] offset:48\n"
    "v_add_u32 v161, 0x4000, v161\n"
    "global_load_dwordx4 v[80:83], v161, s[8:9]\n"
    "global_load_dwordx4 v[84:87], v161, s[8:9] offset:16\n"
    "global_load_dwordx4 v[88:91], v161, s[8:9] offset:32\n"
    "global_load_dwordx4 v[92:95], v161, s[8:9] offset:48\n"
    // ---- xp bank A <- block 0 ----
    LOAD_BANK_A
    ADV_XP
    "s_waitcnt vmcnt(0)\n"
    "s_barrier\n"
    // ---- main loop: 2 blocks (16 steps) per iteration ----
    "1:\n"
    LOAD_BANK_B
    ADV_XP
    "s_waitcnt vmcnt(16)\n"
    STEP_E("v96","v97","v98","v99","0")
    STEP_O("v100","v101","v102","v103","256")
    STEP_E("v104","v105","v106","v107","512")
    STEP_O("v108","v109","v110","v111","768")
    STEP_E("v112","v113","v114","v115","1024")
    STEP_O("v116","v117","v118","v119","1280")
    STEP_E("v120","v121","v122","v123","1536")
    STEP_O("v124","v125","v126","v127","1792")
    ADV_HS
    LOAD_BANK_A
    ADV_XP
    "s_waitcnt vmcnt(16)\n"
    STEP_E("v128","v129","v130","v131","0")
    STEP_O("v132","v133","v134","v135","256")
    STEP_E("v136","v137","v138","v139","512")
    STEP_O("v140","v141","v142","v143","768")
    STEP_E("v144","v145","v146","v147","1024")
    STEP_O("v148","v149","v150","v151","1280")
    STEP_E("v152","v153","v154","v155","1536")
    STEP_O("v156","v157","v158","v159","1792")
    ADV_HS
    "s_sub_u32 s6, s6, 1\n"
    "s_cmp_lg_u32 s6, 0\n"
    "s_cbranch_scc1 1b\n"
    :
    : [xpa]"s"(xpa), [hsp]"s"(hsp), [whh]"s"(whh), [nb2]"s"(nb2),
      [hra]"v"(hra), [hwa]"v"(hwa), [hso]"v"(hso), [xpo]"v"(xpo),
      [wof]"v"(wof), [smk]"v"(smk)
    : "memory","scc","vcc",
      "s0","s1","s2","s3","s4","s5","s6","s7","s8","s9","s10","s11","s12","s13",
      "v0","v1","v2","v3","v4","v5","v6","v7","v8","v9","v10","v11","v12","v13","v14","v15",
      "v16","v17","v18","v19","v20","v21","v22","v23","v24","v25","v26","v27","v28","v29","v30","v31",
      "v32","v33","v34","v35","v36","v37","v38","v39","v40","v41","v42","v43","v44","v45","v46","v47",
      "v48","v49","v50","v51","v52","v53","v54","v55","v56","v57","v58","v59","v60","v61","v62","v63",
      "v64","v65","v66","v67","v68","v69","v70","v71","v72","v73","v74","v75","v76","v77","v78","v79",
      "v80","v81","v82","v83","v84","v85","v86","v87","v88","v89","v90","v91","v92","v93","v94","v95",
      "v96","v97","v98","v99","v100","v101","v102","v103","v104","v105","v106","v107","v108","v109","v110","v111",
      "v112","v113","v114","v115","v116","v117","v118","v119","v120","v121","v122","v123","v124","v125","v126","v127",
      "v128","v129","v130","v131","v132","v133","v134","v135","v136","v137","v138","v139","v140","v141","v142","v143",
      "v144","v145","v146","v147","v148","v149","v150","v151","v152","v153","v154","v155","v156","v157","v158","v159",
      "v160","v161");
}

// ---- fallback scan (MODES 1,2) — round-2-verified structure ----------------
template<int MODE>
__global__ __launch_bounds__(256,1) void lstm_scan(
    const float* __restrict__ xp, const float* __restrict__ x,
    const float* __restrict__ W_ih, const float* __restrict__ W_hh,
    const float* __restrict__ b_ih, const float* __restrict__ b_hh,
    const float* __restrict__ W_lin, const float* __restrict__ b_lin,
    const float* __restrict__ W_fin, const float* __restrict__ b_fin,
    float* __restrict__ hs, float* __restrict__ out, int T)
{
  const int tid = threadIdx.x;
  const int w = tid >> 6, l = tid & 63;
  const int gate = l & 3;
  const int u64i = w * 16 + (l >> 2);
  const int row = gate * 64 + u64i;

  float wv[64];
  { const float4* wr = (const float4*)(W_hh + (size_t)row*64);
    #pragma unroll
    for (int k=0;k<16;++k){ float4 q=wr[k]; wv[4*k]=q.x; wv[4*k+1]=q.y; wv[4*k+2]=q.z; wv[4*k+3]=q.w; } }

  const bool isg = (gate == 2);
  const float kscale = isg ? (-2.f*LOG2E) : (-LOG2E);
  const float kmul = isg ? 2.f : 1.f;
  const float kadd = isg ? -1.f : 0.f;
  float c = 0.f;

  __shared__ alignas(16) float hbufs[2][64];
  if (tid < 64){ hbufs[0][tid] = 0.f; hbufs[1][tid] = 0.f; }

  float wih[64]; float bias = 0.f;
  __shared__ alignas(16) float xlds[2][512];
  float px0=0.f, px1=0.f;
  const size_t N = (size_t)T * 64;

  {
    const float4* wr = (const float4*)(W_ih + (size_t)row*64);
    #pragma unroll
    for (int k=0;k<16;++k){ float4 q=wr[k]; wih[4*k]=q.x; wih[4*k+1]=q.y; wih[4*k+2]=q.z; wih[4*k+3]=q.w; }
    bias = b_ih[row] + b_hh[row];
    px0 = x[tid]; px1 = x[(size_t)tid + 256];
    xlds[0][tid] = px0; xlds[0][tid+256] = px1;
    size_t i0 = (size_t)512 + tid, i1 = (size_t)512 + tid + 256;
    px0 = x[i0 < N ? i0 : (N-1)];
    px1 = x[i1 < N ? i1 : (N-1)];
  }

  float wlin[64], blin_l=0.f, wfin_l=0.f, bfin=0.f;
  if (MODE == 2){
    const float4* wr = (const float4*)(W_lin + (size_t)l*64);
    #pragma unroll
    for (int k=0;k<16;++k){ float4 q=wr[k]; wlin[4*k]=q.x; wlin[4*k+1]=q.y; wlin[4*k+2]=q.z; wlin[4*k+3]=q.w; }
    blin_l = b_lin[l]; wfin_l = W_fin[l]; bfin = b_fin[0];
  }

  __syncthreads();

  for (int tb = 0; tb < T; tb += 8){
    {
      const int gi = tb >> 3;
      float* xd = xlds[(gi+1)&1];
      xd[tid] = px0; xd[tid+256] = px1;
      const size_t base = (size_t)(gi+2) * 512;
      size_t i0 = base + tid, i1 = base + tid + 256;
      px0 = x[i0 < N ? i0 : (N-1)];
      px1 = x[i1 < N ? i1 : (N-1)];
    }
    #pragma unroll
    for (int j=0;j<8;++j){
      const int t = tb + j;
      const float4* hbp = (const float4*)hbufs[t&1];
      float a0=0,a1=0,a2=0,a3=0;
      float m0=0,m1=0,m2=0,m3=0;
      #pragma unroll
      for (int k=0;k<16;++k){
        float4 hk = hbp[k];
        a0 = fmaf(wv[4*k+0], hk.x, a0);
        a1 = fmaf(wv[4*k+1], hk.y, a1);
        a2 = fmaf(wv[4*k+2], hk.z, a2);
        a3 = fmaf(wv[4*k+3], hk.w, a3);
        if (MODE == 2){
          m0 = fmaf(wlin[4*k+0], fmaxf(hk.x,0.f), m0);
          m1 = fmaf(wlin[4*k+1], fmaxf(hk.y,0.f), m1);
          m2 = fmaf(wlin[4*k+2], fmaxf(hk.z,0.f), m2);
          m3 = fmaf(wlin[4*k+3], fmaxf(hk.w,0.f), m3);
        }
      }
      float z = (a0+a1)+(a2+a3);
      {
        const float4* xr = (const float4*)&xlds[(tb>>3)&1][j*64];
        float b0=0,b1=0,b2=0,b3=0;
        #pragma unroll
        for (int k=0;k<16;++k){
          float4 q = xr[k];
          b0 = fmaf(wih[4*k+0], q.x, b0);
          b1 = fmaf(wih[4*k+1], q.y, b1);
          b2 = fmaf(wih[4*k+2], q.z, b2);
          b3 = fmaf(wih[4*k+3], q.w, b3);
        }
        z += bias + ((b0+b1)+(b2+b3));
      }
      if (MODE == 2){
        float mid = fmaxf(blin_l + ((m0+m1)+(m2+m3)), 0.f);
        float po = wfin_l * mid;
        if (w == 0){
          po += __shfl_xor(po,1); po += __shfl_xor(po,2); po += __shfl_xor(po,4);
          po += __shfl_xor(po,8); po += __shfl_xor(po,16); po += __shfl_xor(po,32);
          if (l == 0 && t > 0) out[t-1] = po + bfin;
        }
      }
      float e = fast_exp2(z * kscale);
      float sgm = fast_rcp(1.f + e);
      float v = fmaf(sgm, kmul, kadd);
      const float q1 = qperm<0xB1>(v);
      const float q2 = qperm<0x4E>(v);
      const float q3 = qperm<0x1B>(v);
      c = fmaf(q1, c, v * q2);
      const float e2 = fast_exp2((-2.f*LOG2E) * c);
      const float tc = fmaf(fast_rcp(1.f + e2), 2.f, -1.f);
      const float h = q3 * tc;
      if ((l & 3) == 0){
        hbufs[(t&1)^1][u64i] = h;
        if (MODE <= 1) hs[(size_t)t*64 + u64i] = h;
      }
      LDS_BARRIER();
    }
  }
  if (MODE == 2){
    const float4* hbp = (const float4*)hbufs[T&1];
    float m0=0,m1=0,m2=0,m3=0;
    #pragma unroll
    for (int k=0;k<16;++k){
      float4 hk = hbp[k];
      m0 = fmaf(wlin[4*k+0], fmaxf(hk.x,0.f), m0);
      m1 = fmaf(wlin[4*k+1], fmaxf(hk.y,0.f), m1);
      m2 = fmaf(wlin[4*k+2], fmaxf(hk.z,0.f), m2);
      m3 = fmaf(wlin[4*k+3], fmaxf(hk.w,0.f), m3);
    }
    float mid = fmaxf(blin_l + ((m0+m1)+(m2+m3)), 0.f);
    float po = wfin_l * mid;
    if (w == 0){
      po += __shfl_xor(po,1); po += __shfl_xor(po,2); po += __shfl_xor(po,4);
      po += __shfl_xor(po,8); po += __shfl_xor(po,16); po += __shfl_xor(po,32);
      if (l == 0) out[T-1] = po + bfin;
    }
  }
}

__global__ __launch_bounds__(128) void postproc_kernel(
    const float* __restrict__ hs, const float* __restrict__ W_lin,
    const float* __restrict__ b_lin, const float* __restrict__ W_fin,
    const float* __restrict__ b_fin, float* __restrict__ out, int T)
{
  __shared__ alignas(16) float wl[4096];
  __shared__ float ht[128][65];
  __shared__ float sb[64], sw[64];
  const int tid = threadIdx.x;
  #pragma unroll
  for (int i=0;i<32;++i){ int f = tid + i*128; wl[f] = W_lin[f]; }
  if (tid < 64){ sb[tid] = b_lin[tid]; sw[tid] = W_fin[tid]; }
  const size_t t0 = (size_t)blockIdx.x * 128;
  #pragma unroll
  for (int i=0;i<64;++i){ int f = tid + i*128; ht[f>>6][f&63] = hs[t0*64 + f]; }
  __syncthreads();
  float rh[64];
  #pragma unroll
  for (int k=0;k<64;++k) rh[k] = fmaxf(ht[tid][k], 0.f);
  float acc = b_fin[0];
  for (int j=0;j<64;++j){
    const float4* wr = (const float4*)(wl + j*64);
    float m0=sb[j],m1=0,m2=0,m3=0;
    #pragma unroll
    for (int k=0;k<16;++k){
      float4 q = wr[k];
      m0 = fmaf(q.x, rh[4*k+0], m0);
      m1 = fmaf(q.y, rh[4*k+1], m1);
      m2 = fmaf(q.z, rh[4*k+2], m2);
      m3 = fmaf(q.w, rh[4*k+3], m3);
    }
    acc = fmaf(sw[j], fmaxf((m0+m1)+(m2+m3), 0.f), acc);
  }
  out[t0 + tid] = acc;
}

extern "C" void kernel_launch(void* const* d_in, const int* in_sizes, int n_in,
                              void* d_out, int out_size, void* d_ws, size_t ws_size,
                              hipStream_t stream)
{
  const float* x    = (const float*)d_in[0];
  const float* W_ih = (const float*)d_in[1];
  const float* W_hh = (const float*)d_in[2];
  const float* b_ih = (const float*)d_in[3];
  const float* b_hh = (const float*)d_in[4];
  const float* W_lin= (const float*)d_in[5];
  const float* b_lin= (const float*)d_in[6];
  const float* W_fin= (const float*)d_in[7];
  const float* b_fin= (const float*)d_in[8];
  float* out = (float*)d_out;
  const int T = in_sizes[0] / 64;
  const size_t xp_bytes = (size_t)T * 256 * sizeof(float);
  const size_t hs_bytes = (size_t)T * 64 * sizeof(float);

  if (ws_size >= xp_bytes + hs_bytes && (T % 16) == 0 && T >= 32){
    float* xp = (float*)d_ws;
    float* hs = (float*)((char*)d_ws + xp_bytes);
    xproj_kernel<<<T/128, 256, 0, stream>>>(x, W_ih, b_ih, b_hh, xp, T);
    lstm_scan_asm<<<1, 256, 0, stream>>>(xp, W_hh, hs, T);
    postproc_kernel<<<T/128, 128, 0, stream>>>(hs, W_lin, b_lin, W_fin, b_fin, out, T);
  } else if (ws_size >= hs_bytes){
    float* hs = (float*)d_ws;
    lstm_scan<1><<<1, 256, 0, stream>>>(nullptr, x, W_ih, W_hh, b_ih, b_hh,
                                        W_lin, b_lin, W_fin, b_fin, hs, out, T);
    postproc_kernel<<<T/128, 128, 0, stream>>>(hs, W_lin, b_lin, W_fin, b_fin, out, T);
  } else {
    lstm_scan<2><<<1, 256, 0, stream>>>(nullptr, x, W_ih, W_hh, b_ih, b_hh,
                                        W_lin, b_lin, W_fin, b_fin, nullptr, out, T);
  }
}

// Round 9
// 36395.691 us; speedup vs baseline: 1.4069x; 1.0065x over previous
//
#include <hip/hip_runtime.h>
#include <hip/hip_bf16.h>

__device__ __forceinline__ float fast_exp2(float x){
#if __has_builtin(__builtin_amdgcn_exp2f)
  return __builtin_amdgcn_exp2f(x);
#else
  return exp2f(x);
#endif
}
__device__ __forceinline__ float fast_rcp(float x){
#if __has_builtin(__builtin_amdgcn_rcpf)
  return __builtin_amdgcn_rcpf(x);
#else
  return 1.0f/x;
#endif
}

template<int CTRL>
__device__ __forceinline__ float qperm(float v){
  return __int_as_float(__builtin_amdgcn_update_dpp(0, __float_as_int(v), CTRL, 0xF, 0xF, true));
}

#define LDS_BARRIER() __asm__ __volatile__("s_waitcnt lgkmcnt(0)\n\ts_barrier" ::: "memory")
#define LOG2E 1.442695040888963f

// xproj lane->row mapping: tid=(w,l): row = (l&3)*64 + w*16 + (l>>2).
// => float4 at unit u = w*16+(l>>2) holds (zi,zf,zg,zo).
__global__ __launch_bounds__(256) void xproj_kernel(
    const float* __restrict__ x, const float* __restrict__ W_ih,
    const float* __restrict__ b_ih, const float* __restrict__ b_hh,
    float* __restrict__ xp, int T)
{
  const int tid = threadIdx.x;
  const int w = tid >> 6, l = tid & 63;
  const int row = (l & 3) * 64 + w * 16 + (l >> 2);
  float wv[64];
  {
    const float4* wr = (const float4*)(W_ih + (size_t)row*64);
    #pragma unroll
    for (int k=0;k<16;++k){ float4 q = wr[k]; wv[4*k]=q.x; wv[4*k+1]=q.y; wv[4*k+2]=q.z; wv[4*k+3]=q.w; }
  }
  const float bias = b_ih[row] + b_hh[row];
  __shared__ alignas(16) float xs[8][64];
  const int t0 = blockIdx.x * 128;
  for (int tt=0; tt<128; tt+=8){
    __syncthreads();
    xs[tid>>6][tid&63] = x[(size_t)(t0+tt)*64 + tid];
    const int f2i = tid + 256;
    xs[f2i>>6][f2i&63] = x[(size_t)(t0+tt)*64 + f2i];
    __syncthreads();
    #pragma unroll
    for (int j=0;j<8;++j){
      const float4* xr = (const float4*)xs[j];
      float a0=0,a1=0,a2=0,a3=0;
      #pragma unroll
      for (int k=0;k<16;++k){
        float4 q = xr[k];
        a0 = fmaf(wv[4*k+0], q.x, a0);
        a1 = fmaf(wv[4*k+1], q.y, a1);
        a2 = fmaf(wv[4*k+2], q.z, a2);
        a3 = fmaf(wv[4*k+3], q.w, a3);
      }
      xp[(size_t)(t0+tt+j)*256 + tid] = bias + ((a0+a1)+(a2+a3));
    }
  }
}

// ===== full inline-asm scan (v2: half-read + row_ror:4 swap) ================
// Register map (fixed, all clobbered):
//  v0 h-read LDS addr (hbase + s*64 + p*32)  v1 hs voffset (u*4)  v2 h-write addr
//  v3 c   v4-v11 pk accumulators / z   v12-v13 temps
//  v16-v23 h own half (2x b128)   v24-v31 partner half (DPP ror4)
//  v32-v95 W_hh weights (16/gate: [own-half 8 | partner-half 8])
//  v96-v159 xp banks A/B   v160 xp voffset   v161/v162 weight cursors

#define S_READS2(R0,R1) \
  "ds_read_b128 v[16:19], v0 offset:" R0 "\n" \
  "ds_read_b128 v[20:23], v0 offset:" R1 "\n" \
  "s_waitcnt lgkmcnt(0)\n" \
  "s_nop 1\n" \
  "v_mov_b32 v24, v16 row_ror:4 row_mask:0xf bank_mask:0xf\n" \
  "v_mov_b32 v25, v17 row_ror:4 row_mask:0xf bank_mask:0xf\n" \
  "v_mov_b32 v26, v18 row_ror:4 row_mask:0xf bank_mask:0xf\n" \
  "v_mov_b32 v27, v19 row_ror:4 row_mask:0xf bank_mask:0xf\n" \
  "v_mov_b32 v28, v20 row_ror:4 row_mask:0xf bank_mask:0xf\n" \
  "v_mov_b32 v29, v21 row_ror:4 row_mask:0xf bank_mask:0xf\n" \
  "v_mov_b32 v30, v22 row_ror:4 row_mask:0xf bank_mask:0xf\n" \
  "v_mov_b32 v31, v23 row_ror:4 row_mask:0xf bank_mask:0xf\n"

#define S_DOT \
  "v_pk_mul_f32 v[4:5], v[32:33], v[16:17]\n" \
  "v_pk_mul_f32 v[6:7], v[48:49], v[16:17]\n" \
  "v_pk_mul_f32 v[8:9], v[64:65], v[16:17]\n" \
  "v_pk_mul_f32 v[10:11], v[80:81], v[16:17]\n" \
  "v_pk_fma_f32 v[4:5], v[34:35], v[18:19], v[4:5]\n" \
  "v_pk_fma_f32 v[6:7], v[50:51], v[18:19], v[6:7]\n" \
  "v_pk_fma_f32 v[8:9], v[66:67], v[18:19], v[8:9]\n" \
  "v_pk_fma_f32 v[10:11], v[82:83], v[18:19], v[10:11]\n" \
  "v_pk_fma_f32 v[4:5], v[36:37], v[20:21], v[4:5]\n" \
  "v_pk_fma_f32 v[6:7], v[52:53], v[20:21], v[6:7]\n" \
  "v_pk_fma_f32 v[8:9], v[68:69], v[20:21], v[8:9]\n" \
  "v_pk_fma_f32 v[10:11], v[84:85], v[20:21], v[10:11]\n" \
  "v_pk_fma_f32 v[4:5], v[38:39], v[22:23], v[4:5]\n" \
  "v_pk_fma_f32 v[6:7], v[54:55], v[22:23], v[6:7]\n" \
  "v_pk_fma_f32 v[8:9], v[70:71], v[22:23], v[8:9]\n" \
  "v_pk_fma_f32 v[10:11], v[86:87], v[22:23], v[10:11]\n" \
  "v_pk_fma_f32 v[4:5], v[40:41], v[24:25], v[4:5]\n" \
  "v_pk_fma_f32 v[6:7], v[56:57], v[24:25], v[6:7]\n" \
  "v_pk_fma_f32 v[8:9], v[72:73], v[24:25], v[8:9]\n" \
  "v_pk_fma_f32 v[10:11], v[88:89], v[24:25], v[10:11]\n" \
  "v_pk_fma_f32 v[4:5], v[42:43], v[26:27], v[4:5]\n" \
  "v_pk_fma_f32 v[6:7], v[58:59], v[26:27], v[6:7]\n" \
  "v_pk_fma_f32 v[8:9], v[74:75], v[26:27], v[8:9]\n" \
  "v_pk_fma_f32 v[10:11], v[90:91], v[26:27], v[10:11]\n" \
  "v_pk_fma_f32 v[4:5], v[44:45], v[28:29], v[4:5]\n" \
  "v_pk_fma_f32 v[6:7], v[60:61], v[28:29], v[6:7]\n" \
  "v_pk_fma_f32 v[8:9], v[76:77], v[28:29], v[8:9]\n" \
  "v_pk_fma_f32 v[10:11], v[92:93], v[28:29], v[10:11]\n" \
  "v_pk_fma_f32 v[4:5], v[46:47], v[30:31], v[4:5]\n" \
  "v_pk_fma_f32 v[6:7], v[62:63], v[30:31], v[6:7]\n" \
  "v_pk_fma_f32 v[8:9], v[78:79], v[30:31], v[8:9]\n" \
  "v_pk_fma_f32 v[10:11], v[94:95], v[30:31], v[10:11]\n"

// quad butterfly FIRST, then add the (quad-uniform) xp term once (R8-verified)
#define S_REDUCE(X0,X1,X2,X3) \
  "v_add_f32 v4, v4, v5\n" \
  "v_add_f32 v5, v6, v7\n" \
  "v_add_f32 v6, v8, v9\n" \
  "v_add_f32 v7, v10, v11\n" \
  "v_add_f32 v4, v4, v4 quad_perm:[1,0,3,2] row_mask:0xf bank_mask:0xf\n" \
  "v_add_f32 v5, v5, v5 quad_perm:[1,0,3,2] row_mask:0xf bank_mask:0xf\n" \
  "v_add_f32 v6, v6, v6 quad_perm:[1,0,3,2] row_mask:0xf bank_mask:0xf\n" \
  "v_add_f32 v7, v7, v7 quad_perm:[1,0,3,2] row_mask:0xf bank_mask:0xf\n" \
  "v_add_f32 v4, v4, v4 quad_perm:[2,3,0,1] row_mask:0xf bank_mask:0xf\n" \
  "v_add_f32 v5, v5, v5 quad_perm:[2,3,0,1] row_mask:0xf bank_mask:0xf\n" \
  "v_add_f32 v6, v6, v6 quad_perm:[2,3,0,1] row_mask:0xf bank_mask:0xf\n" \
  "v_add_f32 v7, v7, v7 quad_perm:[2,3,0,1] row_mask:0xf bank_mask:0xf\n" \
  "v_add_f32 v4, v4, " X0 "\n" \
  "v_add_f32 v5, v5, " X1 "\n" \
  "v_add_f32 v6, v6, " X2 "\n" \
  "v_add_f32 v7, v7, " X3 "\n"

#define S_NONLIN \
  "v_mul_f32 v8, 0xbfb8aa3b, v4\n" \
  "v_mul_f32 v9, 0xbfb8aa3b, v5\n" \
  "v_mul_f32 v10, 0xc038aa3b, v6\n" \
  "v_mul_f32 v11, 0xbfb8aa3b, v7\n" \
  "v_exp_f32 v8, v8\n" \
  "v_exp_f32 v9, v9\n" \
  "v_exp_f32 v10, v10\n" \
  "v_exp_f32 v11, v11\n" \
  "v_add_f32 v8, 1.0, v8\n" \
  "v_add_f32 v9, 1.0, v9\n" \
  "v_add_f32 v10, 1.0, v10\n" \
  "v_add_f32 v11, 1.0, v11\n" \
  "v_rcp_f32 v8, v8\n" \
  "v_rcp_f32 v9, v9\n" \
  "v_rcp_f32 v10, v10\n" \
  "v_rcp_f32 v11, v11\n" \
  "s_nop 0\n" \
  "v_fma_f32 v10, v10, 2.0, -1.0\n" \
  "v_mul_f32 v12, v8, v10\n" \
  "v_fma_f32 v3, v9, v3, v12\n" \
  "v_mul_f32 v13, 0xc038aa3b, v3\n" \
  "v_exp_f32 v13, v13\n" \
  "s_nop 0\n" \
  "v_add_f32 v13, 1.0, v13\n" \
  "v_rcp_f32 v13, v13\n" \
  "s_nop 0\n" \
  "v_fma_f32 v13, v13, 2.0, -1.0\n" \
  "v_mul_f32 v13, v11, v13\n"

// all 4 slice lanes hold identical h -> same-address writes are benign; no exec mask
#define S_WRITE_SYNC(WR,SO) \
  "ds_write_b32 v2, v13 offset:" WR "\n" \
  "global_store_dword v1, v13, s[4:5] offset:" SO "\n" \
  "s_waitcnt lgkmcnt(0)\n" \
  "s_barrier\n"

#define STEP_E(X0,X1,X2,X3,SO) \
  S_READS2("0","16") S_DOT S_REDUCE(X0,X1,X2,X3) S_NONLIN S_WRITE_SYNC("256",SO)
#define STEP_O(X0,X1,X2,X3,SO) \
  S_READS2("256","272") S_DOT S_REDUCE(X0,X1,X2,X3) S_NONLIN S_WRITE_SYNC("0",SO)

#define LOAD_BANK_B \
  "global_load_dwordx4 v[128:131], v160, s[0:1]\n" \
  "global_load_dwordx4 v[132:135], v160, s[0:1] offset:1024\n" \
  "global_load_dwordx4 v[136:139], v160, s[0:1] offset:2048\n" \
  "global_load_dwordx4 v[140:143], v160, s[0:1] offset:3072\n" \
  "global_load_dwordx4 v[144:147], v160, s[2:3]\n" \
  "global_load_dwordx4 v[148:151], v160, s[2:3] offset:1024\n" \
  "global_load_dwordx4 v[152:155], v160, s[2:3] offset:2048\n" \
  "global_load_dwordx4 v[156:159], v160, s[2:3] offset:3072\n"

#define LOAD_BANK_A \
  "global_load_dwordx4 v[96:99], v160, s[0:1]\n" \
  "global_load_dwordx4 v[100:103], v160, s[0:1] offset:1024\n" \
  "global_load_dwordx4 v[104:107], v160, s[0:1] offset:2048\n" \
  "global_load_dwordx4 v[108:111], v160, s[0:1] offset:3072\n" \
  "global_load_dwordx4 v[112:115], v160, s[2:3]\n" \
  "global_load_dwordx4 v[116:119], v160, s[2:3] offset:1024\n" \
  "global_load_dwordx4 v[120:123], v160, s[2:3] offset:2048\n" \
  "global_load_dwordx4 v[124:127], v160, s[2:3] offset:3072\n"

#define ADV_XP \
  "s_add_u32 s0, s0, 0x2000\n" "s_addc_u32 s1, s1, 0\n" \
  "s_add_u32 s2, s2, 0x2000\n" "s_addc_u32 s3, s3, 0\n"

#define ADV_HS \
  "s_add_u32 s4, s4, 0x800\n" "s_addc_u32 s5, s5, 0\n"

__global__ __launch_bounds__(256,1) void lstm_scan_asm(
    const float* __restrict__ xp, const float* __restrict__ W_hh,
    float* __restrict__ hs, int T)
{
  const int tid = threadIdx.x;
  const int w = tid >> 6, l = tid & 63;
  const int s = l & 3;
  const int u = w * 16 + (l >> 2);
  const int p = (l >> 2) & 1;            // half index within the slice

  __shared__ alignas(16) float hb[2][64];
  if (tid < 64){ hb[0][tid] = 0.f; hb[1][tid] = 0.f; }
  __syncthreads();

  unsigned hbase = (unsigned)(uintptr_t)(__attribute__((address_space(3))) float*)&hb[0][0];
  unsigned hra = hbase + (unsigned)(s * 64 + p * 32);
  unsigned hwa = hbase + (unsigned)(u * 4);
  unsigned hso = (unsigned)(u * 4);
  unsigned xpo = (unsigned)(u * 16);
  unsigned wof0 = (unsigned)(u * 256 + s * 64 + p * 32);
  unsigned wof1 = (unsigned)(u * 256 + s * 64 + (1 - p) * 32);
  unsigned long long xpa = (unsigned long long)(uintptr_t)xp;
  unsigned long long hsp = (unsigned long long)(uintptr_t)hs;
  unsigned long long whh = (unsigned long long)(uintptr_t)W_hh;
  int nb2 = T >> 4;

  __asm__ __volatile__(
    // ---- prologue: fixed-reg init ----
    "s_mov_b64 s[0:1], %[xpa]\n"
    "s_add_u32 s2, s0, 0x1000\n"
    "s_addc_u32 s3, s1, 0\n"
    "s_mov_b64 s[4:5], %[hsp]\n"
    "s_mov_b32 s6, %[nb2]\n"
    "s_mov_b64 s[8:9], %[whh]\n"
    "v_mov_b32 v0, %[hra]\n"
    "v_mov_b32 v1, %[hso]\n"
    "v_mov_b32 v2, %[hwa]\n"
    "v_mov_b32 v160, %[xpo]\n"
    "v_mov_b32 v161, %[wof0]\n"
    "v_mov_b32 v162, %[wof1]\n"
    "v_mov_b32 v3, 0\n"
    // ---- weights: 4 gates x (own-half 2x dwordx4, partner-half 2x dwordx4) ----
    "global_load_dwordx4 v[32:35], v161, s[8:9]\n"
    "global_load_dwordx4 v[36:39], v161, s[8:9] offset:16\n"
    "global_load_dwordx4 v[40:43], v162, s[8:9]\n"
    "global_load_dwordx4 v[44:47], v162, s[8:9] offset:16\n"
    "v_add_u32 v161, 0x4000, v161\n"
    "v_add_u32 v162, 0x4000, v162\n"
    "global_load_dwordx4 v[48:51], v161, s[8:9]\n"
    "global_load_dwordx4 v[52:55], v161, s[8:9] offset:16\n"
    "global_load_dwordx4 v[56:59], v162, s[8:9]\n"
    "global_load_dwordx4 v[60:63], v162, s[8:9] offset:16\n"
    "v_add_u32 v161, 0x4000, v161\n"
    "v_add_u32 v162, 0x4000, v162\n"
    "global_load_dwordx4 v[64:67], v161, s[8:9]\n"
    "global_load_dwordx4 v[68:71], v161, s[8:9] offset:16\n"
    "global_load_dwordx4 v[72:75], v162, s[8:9]\n"
    "global_load_dwordx4 v[76:79], v162, s[8:9] offset:16\n"
    "v_add_u32 v161, 0x4000, v161\n"
    "v_add_u32 v162, 0x4000, v162\n"
    "global_load_dwordx4 v[80:83], v161, s[8:9]\n"
    "global_load_dwordx4 v[84:87], v161, s[8:9] offset:16\n"
    "global_load_dwordx4 v[88:91], v162, s[8:9]\n"
    "global_load_dwordx4 v[92:95], v162, s[8:9] offset:16\n"
    // ---- xp bank A <- block 0 ----
    LOAD_BANK_A
    ADV_XP
    "s_waitcnt vmcnt(0)\n"
    "s_barrier\n"
    // ---- main loop: 2 blocks (16 steps) per iteration ----
    "1:\n"
    LOAD_BANK_B
    ADV_XP
    "s_waitcnt vmcnt(16)\n"
    STEP_E("v96","v97","v98","v99","0")
    STEP_O("v100","v101","v102","v103","256")
    STEP_E("v104","v105","v106","v107","512")
    STEP_O("v108","v109","v110","v111","768")
    STEP_E("v112","v113","v114","v115","1024")
    STEP_O("v116","v117","v118","v119","1280")
    STEP_E("v120","v121","v122","v123","1536")
    STEP_O("v124","v125","v126","v127","1792")
    ADV_HS
    LOAD_BANK_A
    ADV_XP
    "s_waitcnt vmcnt(16)\n"
    STEP_E("v128","v129","v130","v131","0")
    STEP_O("v132","v133","v134","v135","256")
    STEP_E("v136","v137","v138","v139","512")
    STEP_O("v140","v141","v142","v143","768")
    STEP_E("v144","v145","v146","v147","1024")
    STEP_O("v148","v149","v150","v151","1280")
    STEP_E("v152","v153","v154","v155","1536")
    STEP_O("v156","v157","v158","v159","1792")
    ADV_HS
    "s_sub_u32 s6, s6, 1\n"
    "s_cmp_lg_u32 s6, 0\n"
    "s_cbranch_scc1 1b\n"
    :
    : [xpa]"s"(xpa), [hsp]"s"(hsp), [whh]"s"(whh), [nb2]"s"(nb2),
      [hra]"v"(hra), [hwa]"v"(hwa), [hso]"v"(hso), [xpo]"v"(xpo),
      [wof0]"v"(wof0), [wof1]"v"(wof1)
    : "memory","scc","vcc",
      "s0","s1","s2","s3","s4","s5","s6","s7","s8","s9","s10","s11","s12","s13",
      "v0","v1","v2","v3","v4","v5","v6","v7","v8","v9","v10","v11","v12","v13","v14","v15",
      "v16","v17","v18","v19","v20","v21","v22","v23","v24","v25","v26","v27","v28","v29","v30","v31",
      "v32","v33","v34","v35","v36","v37","v38","v39","v40","v41","v42","v43","v44","v45","v46","v47",
      "v48","v49","v50","v51","v52","v53","v54","v55","v56","v57","v58","v59","v60","v61","v62","v63",
      "v64","v65","v66","v67","v68","v69","v70","v71","v72","v73","v74","v75","v76","v77","v78","v79",
      "v80","v81","v82","v83","v84","v85","v86","v87","v88","v89","v90","v91","v92","v93","v94","v95",
      "v96","v97","v98","v99","v100","v101","v102","v103","v104","v105","v106","v107","v108","v109","v110","v111",
      "v112","v113","v114","v115","v116","v117","v118","v119","v120","v121","v122","v123","v124","v125","v126","v127",
      "v128","v129","v130","v131","v132","v133","v134","v135","v136","v137","v138","v139","v140","v141","v142","v143",
      "v144","v145","v146","v147","v148","v149","v150","v151","v152","v153","v154","v155","v156","v157","v158","v159",
      "v160","v161","v162");
}

// ---- fallback scan (MODES 1,2) — round-2-verified structure ----------------
template<int MODE>
__global__ __launch_bounds__(256,1) void lstm_scan(
    const float* __restrict__ xp, const float* __restrict__ x,
    const float* __restrict__ W_ih, const float* __restrict__ W_hh,
    const float* __restrict__ b_ih, const float* __restrict__ b_hh,
    const float* __restrict__ W_lin, const float* __restrict__ b_lin,
    const float* __restrict__ W_fin, const float* __restrict__ b_fin,
    float* __restrict__ hs, float* __restrict__ out, int T)
{
  const int tid = threadIdx.x;
  const int w = tid >> 6, l = tid & 63;
  const int gate = l & 3;
  const int u64i = w * 16 + (l >> 2);
  const int row = gate * 64 + u64i;

  float wv[64];
  { const float4* wr = (const float4*)(W_hh + (size_t)row*64);
    #pragma unroll
    for (int k=0;k<16;++k){ float4 q=wr[k]; wv[4*k]=q.x; wv[4*k+1]=q.y; wv[4*k+2]=q.z; wv[4*k+3]=q.w; } }

  const bool isg = (gate == 2);
  const float kscale = isg ? (-2.f*LOG2E) : (-LOG2E);
  const float kmul = isg ? 2.f : 1.f;
  const float kadd = isg ? -1.f : 0.f;
  float c = 0.f;

  __shared__ alignas(16) float hbufs[2][64];
  if (tid < 64){ hbufs[0][tid] = 0.f; hbufs[1][tid] = 0.f; }

  float wih[64]; float bias = 0.f;
  __shared__ alignas(16) float xlds[2][512];
  float px0=0.f, px1=0.f;
  const size_t N = (size_t)T * 64;

  {
    const float4* wr = (const float4*)(W_ih + (size_t)row*64);
    #pragma unroll
    for (int k=0;k<16;++k){ float4 q=wr[k]; wih[4*k]=q.x; wih[4*k+1]=q.y; wih[4*k+2]=q.z; wih[4*k+3]=q.w; }
    bias = b_ih[row] + b_hh[row];
    px0 = x[tid]; px1 = x[(size_t)tid + 256];
    xlds[0][tid] = px0; xlds[0][tid+256] = px1;
    size_t i0 = (size_t)512 + tid, i1 = (size_t)512 + tid + 256;
    px0 = x[i0 < N ? i0 : (N-1)];
    px1 = x[i1 < N ? i1 : (N-1)];
  }

  float wlin[64], blin_l=0.f, wfin_l=0.f, bfin=0.f;
  if (MODE == 2){
    const float4* wr = (const float4*)(W_lin + (size_t)l*64);
    #pragma unroll
    for (int k=0;k<16;++k){ float4 q=wr[k]; wlin[4*k]=q.x; wlin[4*k+1]=q.y; wlin[4*k+2]=q.z; wlin[4*k+3]=q.w; }
    blin_l = b_lin[l]; wfin_l = W_fin[l]; bfin = b_fin[0];
  }

  __syncthreads();

  for (int tb = 0; tb < T; tb += 8){
    {
      const int gi = tb >> 3;
      float* xd = xlds[(gi+1)&1];
      xd[tid] = px0; xd[tid+256] = px1;
      const size_t base = (size_t)(gi+2) * 512;
      size_t i0 = base + tid, i1 = base + tid + 256;
      px0 = x[i0 < N ? i0 : (N-1)];
      px1 = x[i1 < N ? i1 : (N-1)];
    }
    #pragma unroll
    for (int j=0;j<8;++j){
      const int t = tb + j;
      const float4* hbp = (const float4*)hbufs[t&1];
      float a0=0,a1=0,a2=0,a3=0;
      float m0=0,m1=0,m2=0,m3=0;
      #pragma unroll
      for (int k=0;k<16;++k){
        float4 hk = hbp[k];
        a0 = fmaf(wv[4*k+0], hk.x, a0);
        a1 = fmaf(wv[4*k+1], hk.y, a1);
        a2 = fmaf(wv[4*k+2], hk.z, a2);
        a3 = fmaf(wv[4*k+3], hk.w, a3);
        if (MODE == 2){
          m0 = fmaf(wlin[4*k+0], fmaxf(hk.x,0.f), m0);
          m1 = fmaf(wlin[4*k+1], fmaxf(hk.y,0.f), m1);
          m2 = fmaf(wlin[4*k+2], fmaxf(hk.z,0.f), m2);
          m3 = fmaf(wlin[4*k+3], fmaxf(hk.w,0.f), m3);
        }
      }
      float z = (a0+a1)+(a2+a3);
      {
        const float4* xr = (const float4*)&xlds[(tb>>3)&1][j*64];
        float b0=0,b1=0,b2=0,b3=0;
        #pragma unroll
        for (int k=0;k<16;++k){
          float4 q = xr[k];
          b0 = fmaf(wih[4*k+0], q.x, b0);
          b1 = fmaf(wih[4*k+1], q.y, b1);
          b2 = fmaf(wih[4*k+2], q.z, b2);
          b3 = fmaf(wih[4*k+3], q.w, b3);
        }
        z += bias + ((b0+b1)+(b2+b3));
      }
      if (MODE == 2){
        float mid = fmaxf(blin_l + ((m0+m1)+(m2+m3)), 0.f);
        float po = wfin_l * mid;
        if (w == 0){
          po += __shfl_xor(po,1); po += __shfl_xor(po,2); po += __shfl_xor(po,4);
          po += __shfl_xor(po,8); po += __shfl_xor(po,16); po += __shfl_xor(po,32);
          if (l == 0 && t > 0) out[t-1] = po + bfin;
        }
      }
      float e = fast_exp2(z * kscale);
      float sgm = fast_rcp(1.f + e);
      float v = fmaf(sgm, kmul, kadd);
      const float q1 = qperm<0xB1>(v);
      const float q2 = qperm<0x4E>(v);
      const float q3 = qperm<0x1B>(v);
      c = fmaf(q1, c, v * q2);
      const float e2 = fast_exp2((-2.f*LOG2E) * c);
      const float tc = fmaf(fast_rcp(1.f + e2), 2.f, -1.f);
      const float h = q3 * tc;
      if ((l & 3) == 0){
        hbufs[(t&1)^1][u64i] = h;
        if (MODE <= 1) hs[(size_t)t*64 + u64i] = h;
      }
      LDS_BARRIER();
    }
  }
  if (MODE == 2){
    const float4* hbp = (const float4*)hbufs[T&1];
    float m0=0,m1=0,m2=0,m3=0;
    #pragma unroll
    for (int k=0;k<16;++k){
      float4 hk = hbp[k];
      m0 = fmaf(wlin[4*k+0], fmaxf(hk.x,0.f), m0);
      m1 = fmaf(wlin[4*k+1], fmaxf(hk.y,0.f), m1);
      m2 = fmaf(wlin[4*k+2], fmaxf(hk.z,0.f), m2);
      m3 = fmaf(wlin[4*k+3], fmaxf(hk.w,0.f), m3);
    }
    float mid = fmaxf(blin_l + ((m0+m1)+(m2+m3)), 0.f);
    float po = wfin_l * mid;
    if (w == 0){
      po += __shfl_xor(po,1); po += __shfl_xor(po,2); po += __shfl_xor(po,4);
      po += __shfl_xor(po,8); po += __shfl_xor(po,16); po += __shfl_xor(po,32);
      if (l == 0) out[T-1] = po + bfin;
    }
  }
}

__global__ __launch_bounds__(128) void postproc_kernel(
    const float* __restrict__ hs, const float* __restrict__ W_lin,
    const float* __restrict__ b_lin, const float* __restrict__ W_fin,
    const float* __restrict__ b_fin, float* __restrict__ out, int T)
{
  __shared__ alignas(16) float wl[4096];
  __shared__ float ht[128][65];
  __shared__ float sb[64], sw[64];
  const int tid = threadIdx.x;
  #pragma unroll
  for (int i=0;i<32;++i){ int f = tid + i*128; wl[f] = W_lin[f]; }
  if (tid < 64){ sb[tid] = b_lin[tid]; sw[tid] = W_fin[tid]; }
  const size_t t0 = (size_t)blockIdx.x * 128;
  #pragma unroll
  for (int i=0;i<64;++i){ int f = tid + i*128; ht[f>>6][f&63] = hs[t0*64 + f]; }
  __syncthreads();
  float rh[64];
  #pragma unroll
  for (int k=0;k<64;++k) rh[k] = fmaxf(ht[tid][k], 0.f);
  float acc = b_fin[0];
  for (int j=0;j<64;++j){
    const float4* wr = (const float4*)(wl + j*64);
    float m0=sb[j],m1=0,m2=0,m3=0;
    #pragma unroll
    for (int k=0;k<16;++k){
      float4 q = wr[k];
      m0 = fmaf(q.x, rh[4*k+0], m0);
      m1 = fmaf(q.y, rh[4*k+1], m1);
      m2 = fmaf(q.z, rh[4*k+2], m2);
      m3 = fmaf(q.w, rh[4*k+3], m3);
    }
    acc = fmaf(sw[j], fmaxf((m0+m1)+(m2+m3), 0.f), acc);
  }
  out[t0 + tid] = acc;
}

extern "C" void kernel_launch(void* const* d_in, const int* in_sizes, int n_in,
                              void* d_out, int out_size, void* d_ws, size_t ws_size,
                              hipStream_t stream)
{
  const float* x    = (const float*)d_in[0];
  const float* W_ih = (const float*)d_in[1];
  const float* W_hh = (const float*)d_in[2];
  const float* b_ih = (const float*)d_in[3];
  const float* b_hh = (const float*)d_in[4];
  const float* W_lin= (const float*)d_in[5];
  const float* b_lin= (const float*)d_in[6];
  const float* W_fin= (const float*)d_in[7];
  const float* b_fin= (const float*)d_in[8];
  float* out = (float*)d_out;
  const int T = in_sizes[0] / 64;
  const size_t xp_bytes = (size_t)T * 256 * sizeof(float);
  const size_t hs_bytes = (size_t)T * 64 * sizeof(float);

  if (ws_size >= xp_bytes + hs_bytes && (T % 16) == 0 && T >= 32){
    float* xp = (float*)d_ws;
    float* hs = (float*)((char*)d_ws + xp_bytes);
    xproj_kernel<<<T/128, 256, 0, stream>>>(x, W_ih, b_ih, b_hh, xp, T);
    lstm_scan_asm<<<1, 256, 0, stream>>>(xp, W_hh, hs, T);
    postproc_kernel<<<T/128, 128, 0, stream>>>(hs, W_lin, b_lin, W_fin, b_fin, out, T);
  } else if (ws_size >= hs_bytes){
    float* hs = (float*)d_ws;
    lstm_scan<1><<<1, 256, 0, stream>>>(nullptr, x, W_ih, W_hh, b_ih, b_hh,
                                        W_lin, b_lin, W_fin, b_fin, hs, out, T);
    postproc_kernel<<<T/128, 128, 0, stream>>>(hs, W_lin, b_lin, W_fin, b_fin, out, T);
  } else {
    lstm_scan<2><<<1, 256, 0, stream>>>(nullptr, x, W_ih, W_hh, b_ih, b_hh,
                                        W_lin, b_lin, W_fin, b_fin, nullptr, out, T);
  }
}

// Round 10
// 34404.437 us; speedup vs baseline: 1.4884x; 1.0579x over previous
//
#include <hip/hip_runtime.h>
#include <hip/hip_bf16.h>

__device__ __forceinline__ float fast_exp2(float x){
#if __has_builtin(__builtin_amdgcn_exp2f)
  return __builtin_amdgcn_exp2f(x);
#else
  return exp2f(x);
#endif
}
__device__ __forceinline__ float fast_rcp(float x){
#if __has_builtin(__builtin_amdgcn_rcpf)
  return __builtin_amdgcn_rcpf(x);
#else
  return 1.0f/x;
#endif
}

template<int CTRL>
__device__ __forceinline__ float qperm(float v){
  return __int_as_float(__builtin_amdgcn_update_dpp(0, __float_as_int(v), CTRL, 0xF, 0xF, true));
}

#define LDS_BARRIER() __asm__ __volatile__("s_waitcnt lgkmcnt(0)\n\ts_barrier" ::: "memory")
#define LOG2E 1.442695040888963f

// xproj lane->row mapping: tid=(w,l): row = (l&3)*64 + w*16 + (l>>2).
__global__ __launch_bounds__(256) void xproj_kernel(
    const float* __restrict__ x, const float* __restrict__ W_ih,
    const float* __restrict__ b_ih, const float* __restrict__ b_hh,
    float* __restrict__ xp, int T)
{
  const int tid = threadIdx.x;
  const int w = tid >> 6, l = tid & 63;
  const int row = (l & 3) * 64 + w * 16 + (l >> 2);
  float wv[64];
  {
    const float4* wr = (const float4*)(W_ih + (size_t)row*64);
    #pragma unroll
    for (int k=0;k<16;++k){ float4 q = wr[k]; wv[4*k]=q.x; wv[4*k+1]=q.y; wv[4*k+2]=q.z; wv[4*k+3]=q.w; }
  }
  const float bias = b_ih[row] + b_hh[row];
  __shared__ alignas(16) float xs[8][64];
  const int t0 = blockIdx.x * 128;
  for (int tt=0; tt<128; tt+=8){
    __syncthreads();
    xs[tid>>6][tid&63] = x[(size_t)(t0+tt)*64 + tid];
    const int f2i = tid + 256;
    xs[f2i>>6][f2i&63] = x[(size_t)(t0+tt)*64 + f2i];
    __syncthreads();
    #pragma unroll
    for (int j=0;j<8;++j){
      const float4* xr = (const float4*)xs[j];
      float a0=0,a1=0,a2=0,a3=0;
      #pragma unroll
      for (int k=0;k<16;++k){
        float4 q = xr[k];
        a0 = fmaf(wv[4*k+0], q.x, a0);
        a1 = fmaf(wv[4*k+1], q.y, a1);
        a2 = fmaf(wv[4*k+2], q.z, a2);
        a3 = fmaf(wv[4*k+3], q.w, a3);
      }
      xp[(size_t)(t0+tt+j)*256 + tid] = bias + ((a0+a1)+(a2+a3));
    }
  }
}

// ===== full inline-asm scan (v3: transpose-reduce + gate-split nonlin) ======
// lane (w,l): s=l&3 (k-slice AND owned gate), u=w*16+(l>>2), p=(l>>2)&1.
// v0 h-read addr  v1 hs voffset  v2 h-write addr  v3 c  v4-v13 work
// v16-23 h own half, v24-31 partner half (ror4)   v32-95 W_hh halves
// v96-103 xp bank A, v104-111 bank B (per-lane dwords)
// v160 xp voffset (tid*4)  v161/162* cursors  v162-164 kscale/kmul/kadd
// s[10:11] gate0 mask  s[14:15] s&1 mask  s[16:17] s&2 mask

#define S_READS2(R0,R1) \
  "ds_read_b128 v[16:19], v0 offset:" R0 "\n" \
  "ds_read_b128 v[20:23], v0 offset:" R1 "\n" \
  "s_waitcnt lgkmcnt(0)\n" \
  "s_nop 1\n" \
  "v_mov_b32 v24, v16 row_ror:4 row_mask:0xf bank_mask:0xf\n" \
  "v_mov_b32 v25, v17 row_ror:4 row_mask:0xf bank_mask:0xf\n" \
  "v_mov_b32 v26, v18 row_ror:4 row_mask:0xf bank_mask:0xf\n" \
  "v_mov_b32 v27, v19 row_ror:4 row_mask:0xf bank_mask:0xf\n" \
  "v_mov_b32 v28, v20 row_ror:4 row_mask:0xf bank_mask:0xf\n" \
  "v_mov_b32 v29, v21 row_ror:4 row_mask:0xf bank_mask:0xf\n" \
  "v_mov_b32 v30, v22 row_ror:4 row_mask:0xf bank_mask:0xf\n" \
  "v_mov_b32 v31, v23 row_ror:4 row_mask:0xf bank_mask:0xf\n"

#define S_DOT \
  "v_pk_mul_f32 v[4:5], v[32:33], v[16:17]\n" \
  "v_pk_mul_f32 v[6:7], v[48:49], v[16:17]\n" \
  "v_pk_mul_f32 v[8:9], v[64:65], v[16:17]\n" \
  "v_pk_mul_f32 v[10:11], v[80:81], v[16:17]\n" \
  "v_pk_fma_f32 v[4:5], v[34:35], v[18:19], v[4:5]\n" \
  "v_pk_fma_f32 v[6:7], v[50:51], v[18:19], v[6:7]\n" \
  "v_pk_fma_f32 v[8:9], v[66:67], v[18:19], v[8:9]\n" \
  "v_pk_fma_f32 v[10:11], v[82:83], v[18:19], v[10:11]\n" \
  "v_pk_fma_f32 v[4:5], v[36:37], v[20:21], v[4:5]\n" \
  "v_pk_fma_f32 v[6:7], v[52:53], v[20:21], v[6:7]\n" \
  "v_pk_fma_f32 v[8:9], v[68:69], v[20:21], v[8:9]\n" \
  "v_pk_fma_f32 v[10:11], v[84:85], v[20:21], v[10:11]\n" \
  "v_pk_fma_f32 v[4:5], v[38:39], v[22:23], v[4:5]\n" \
  "v_pk_fma_f32 v[6:7], v[54:55], v[22:23], v[6:7]\n" \
  "v_pk_fma_f32 v[8:9], v[70:71], v[22:23], v[8:9]\n" \
  "v_pk_fma_f32 v[10:11], v[86:87], v[22:23], v[10:11]\n" \
  "v_pk_fma_f32 v[4:5], v[40:41], v[24:25], v[4:5]\n" \
  "v_pk_fma_f32 v[6:7], v[56:57], v[24:25], v[6:7]\n" \
  "v_pk_fma_f32 v[8:9], v[72:73], v[24:25], v[8:9]\n" \
  "v_pk_fma_f32 v[10:11], v[88:89], v[24:25], v[10:11]\n" \
  "v_pk_fma_f32 v[4:5], v[42:43], v[26:27], v[4:5]\n" \
  "v_pk_fma_f32 v[6:7], v[58:59], v[26:27], v[6:7]\n" \
  "v_pk_fma_f32 v[8:9], v[74:75], v[26:27], v[8:9]\n" \
  "v_pk_fma_f32 v[10:11], v[90:91], v[26:27], v[10:11]\n" \
  "v_pk_fma_f32 v[4:5], v[44:45], v[28:29], v[4:5]\n" \
  "v_pk_fma_f32 v[6:7], v[60:61], v[28:29], v[6:7]\n" \
  "v_pk_fma_f32 v[8:9], v[76:77], v[28:29], v[8:9]\n" \
  "v_pk_fma_f32 v[10:11], v[92:93], v[28:29], v[10:11]\n" \
  "v_pk_fma_f32 v[4:5], v[46:47], v[30:31], v[4:5]\n" \
  "v_pk_fma_f32 v[6:7], v[62:63], v[30:31], v[6:7]\n" \
  "v_pk_fma_f32 v[8:9], v[78:79], v[30:31], v[8:9]\n" \
  "v_pk_fma_f32 v[10:11], v[94:95], v[30:31], v[10:11]\n"

// Transpose-reduce: lane s ends with the FULL quad-sum of gate s, + xp once.
// Same per-gate summation order as the R8/R9 butterfly (self+xor1, then xor2).
#define S_TRED(X) \
  "v_add_f32 v4, v4, v5\n" \
  "v_add_f32 v5, v6, v7\n" \
  "v_add_f32 v6, v8, v9\n" \
  "v_add_f32 v7, v10, v11\n" \
  "v_cndmask_b32 v8, v5, v4, s[14:15]\n" \
  "v_cndmask_b32 v9, v7, v6, s[14:15]\n" \
  "v_cndmask_b32 v10, v4, v5, s[14:15]\n" \
  "v_cndmask_b32 v11, v6, v7, s[14:15]\n" \
  "v_mov_b32 v12, v8 quad_perm:[1,0,3,2] row_mask:0xf bank_mask:0xf\n" \
  "v_mov_b32 v13, v9 quad_perm:[1,0,3,2] row_mask:0xf bank_mask:0xf\n" \
  "v_add_f32 v4, v10, v12\n" \
  "v_add_f32 v5, v11, v13\n" \
  "v_cndmask_b32 v8, v5, v4, s[16:17]\n" \
  "v_cndmask_b32 v9, v4, v5, s[16:17]\n" \
  "s_nop 1\n" \
  "v_mov_b32 v10, v8 quad_perm:[2,3,0,1] row_mask:0xf bank_mask:0xf\n" \
  "v_add_f32 v4, v9, v10\n" \
  "v_add_f32 v4, v4, " X "\n"

// Per-lane nonlin for OWN gate (2 trans), quad exchange, c/tanh (2 trans).
// Valid c/h in gate0 lanes only (v5=i, v8=f, v9=g, v10=o there).
#define S_NONLIN2 \
  "v_mul_f32 v5, v4, v162\n" \
  "v_exp_f32 v5, v5\n" \
  "s_nop 0\n" \
  "v_add_f32 v5, 1.0, v5\n" \
  "v_rcp_f32 v5, v5\n" \
  "s_nop 0\n" \
  "v_fma_f32 v5, v5, v163, v164\n" \
  "s_nop 1\n" \
  "v_mov_b32 v8, v5 quad_perm:[1,0,3,2] row_mask:0xf bank_mask:0xf\n" \
  "v_mov_b32 v9, v5 quad_perm:[2,3,0,1] row_mask:0xf bank_mask:0xf\n" \
  "v_mov_b32 v10, v5 quad_perm:[3,2,1,0] row_mask:0xf bank_mask:0xf\n" \
  "v_mul_f32 v11, v5, v9\n" \
  "v_fma_f32 v3, v8, v3, v11\n" \
  "v_mul_f32 v12, 0xc038aa3b, v3\n" \
  "v_exp_f32 v12, v12\n" \
  "s_nop 0\n" \
  "v_add_f32 v12, 1.0, v12\n" \
  "v_rcp_f32 v12, v12\n" \
  "s_nop 0\n" \
  "v_fma_f32 v12, v12, 2.0, -1.0\n" \
  "v_mul_f32 v13, v10, v12\n"

// exec-masked write: only gate0 lanes hold valid h (R8-verified pattern)
#define S_WRITE_SYNC(WR,SO) \
  "s_and_saveexec_b64 s[12:13], s[10:11]\n" \
  "ds_write_b32 v2, v13 offset:" WR "\n" \
  "global_store_dword v1, v13, s[4:5] offset:" SO "\n" \
  "s_mov_b64 exec, s[12:13]\n" \
  "s_waitcnt lgkmcnt(0)\n" \
  "s_barrier\n"

#define STEP_E(X,SO) \
  S_READS2("0","16") S_DOT S_TRED(X) S_NONLIN2 S_WRITE_SYNC("256",SO)
#define STEP_O(X,SO) \
  S_READS2("256","272") S_DOT S_TRED(X) S_NONLIN2 S_WRITE_SYNC("0",SO)

#define LOAD_BANK_A \
  "global_load_dword v96, v160, s[0:1]\n" \
  "global_load_dword v97, v160, s[0:1] offset:1024\n" \
  "global_load_dword v98, v160, s[0:1] offset:2048\n" \
  "global_load_dword v99, v160, s[0:1] offset:3072\n" \
  "global_load_dword v100, v160, s[2:3]\n" \
  "global_load_dword v101, v160, s[2:3] offset:1024\n" \
  "global_load_dword v102, v160, s[2:3] offset:2048\n" \
  "global_load_dword v103, v160, s[2:3] offset:3072\n"

#define LOAD_BANK_B \
  "global_load_dword v104, v160, s[0:1]\n" \
  "global_load_dword v105, v160, s[0:1] offset:1024\n" \
  "global_load_dword v106, v160, s[0:1] offset:2048\n" \
  "global_load_dword v107, v160, s[0:1] offset:3072\n" \
  "global_load_dword v108, v160, s[2:3]\n" \
  "global_load_dword v109, v160, s[2:3] offset:1024\n" \
  "global_load_dword v110, v160, s[2:3] offset:2048\n" \
  "global_load_dword v111, v160, s[2:3] offset:3072\n"

#define ADV_XP \
  "s_add_u32 s0, s0, 0x2000\n" "s_addc_u32 s1, s1, 0\n" \
  "s_add_u32 s2, s2, 0x2000\n" "s_addc_u32 s3, s3, 0\n"

#define ADV_HS \
  "s_add_u32 s4, s4, 0x800\n" "s_addc_u32 s5, s5, 0\n"

__global__ __launch_bounds__(256,1) void lstm_scan_asm(
    const float* __restrict__ xp, const float* __restrict__ W_hh,
    float* __restrict__ hs, int T)
{
  const int tid = threadIdx.x;
  const int w = tid >> 6, l = tid & 63;
  const int s = l & 3;
  const int u = w * 16 + (l >> 2);
  const int p = (l >> 2) & 1;

  __shared__ alignas(16) float hb[2][64];
  if (tid < 64){ hb[0][tid] = 0.f; hb[1][tid] = 0.f; }
  __syncthreads();

  unsigned hbase = (unsigned)(uintptr_t)(__attribute__((address_space(3))) float*)&hb[0][0];
  unsigned hra = hbase + (unsigned)(s * 64 + p * 32);
  unsigned hwa = hbase + (unsigned)(u * 4);
  unsigned hso = (unsigned)(u * 4);
  unsigned xpo = (unsigned)(tid * 4);
  unsigned wof0 = (unsigned)(u * 256 + s * 64 + p * 32);
  unsigned wof1 = (unsigned)(u * 256 + s * 64 + (1 - p) * 32);
  unsigned sv = (unsigned)s;
  unsigned b0 = (unsigned)(s & 1);
  unsigned b1 = (unsigned)((s >> 1) & 1);
  float ksc = (s == 2) ? (-2.f*LOG2E) : (-LOG2E);
  float kml = (s == 2) ? 2.f : 1.f;
  float kad = (s == 2) ? -1.f : 0.f;
  unsigned long long xpa = (unsigned long long)(uintptr_t)xp;
  unsigned long long hsp = (unsigned long long)(uintptr_t)hs;
  unsigned long long whh = (unsigned long long)(uintptr_t)W_hh;
  int nb2 = T >> 4;

  __asm__ __volatile__(
    // ---- prologue ----
    "s_mov_b64 s[0:1], %[xpa]\n"
    "s_add_u32 s2, s0, 0x1000\n"
    "s_addc_u32 s3, s1, 0\n"
    "s_mov_b64 s[4:5], %[hsp]\n"
    "s_mov_b32 s6, %[nb2]\n"
    "s_mov_b64 s[8:9], %[whh]\n"
    "v_mov_b32 v0, %[hra]\n"
    "v_mov_b32 v1, %[hso]\n"
    "v_mov_b32 v2, %[hwa]\n"
    "v_mov_b32 v160, %[xpo]\n"
    "v_mov_b32 v161, %[wof0]\n"
    "v_mov_b32 v165, %[wof1]\n"
    "v_mov_b32 v162, %[ksc]\n"
    "v_mov_b32 v163, %[kml]\n"
    "v_mov_b32 v164, %[kad]\n"
    "v_mov_b32 v3, 0\n"
    "v_cmp_eq_u32 vcc, 0, %[sv]\n"
    "s_nop 4\n"
    "s_mov_b64 s[10:11], vcc\n"
    "v_cmp_eq_u32 vcc, 1, %[b0]\n"
    "s_nop 4\n"
    "s_mov_b64 s[14:15], vcc\n"
    "v_cmp_eq_u32 vcc, 1, %[b1]\n"
    "s_nop 4\n"
    "s_mov_b64 s[16:17], vcc\n"
    // ---- weights: 4 gates x (own-half 2x dwordx4, partner-half 2x dwordx4) ----
    "global_load_dwordx4 v[32:35], v161, s[8:9]\n"
    "global_load_dwordx4 v[36:39], v161, s[8:9] offset:16\n"
    "global_load_dwordx4 v[40:43], v165, s[8:9]\n"
    "global_load_dwordx4 v[44:47], v165, s[8:9] offset:16\n"
    "v_add_u32 v161, 0x4000, v161\n"
    "v_add_u32 v165, 0x4000, v165\n"
    "global_load_dwordx4 v[48:51], v161, s[8:9]\n"
    "global_load_dwordx4 v[52:55], v161, s[8:9] offset:16\n"
    "global_load_dwordx4 v[56:59], v165, s[8:9]\n"
    "global_load_dwordx4 v[60:63], v165, s[8:9] offset:16\n"
    "v_add_u32 v161, 0x4000, v161\n"
    "v_add_u32 v165, 0x4000, v165\n"
    "global_load_dwordx4 v[64:67], v161, s[8:9]\n"
    "global_load_dwordx4 v[68:71], v161, s[8:9] offset:16\n"
    "global_load_dwordx4 v[72:75], v165, s[8:9]\n"
    "global_load_dwordx4 v[76:79], v165, s[8:9] offset:16\n"
    "v_add_u32 v161, 0x4000, v161\n"
    "v_add_u32 v165, 0x4000, v165\n"
    "global_load_dwordx4 v[80:83], v161, s[8:9]\n"
    "global_load_dwordx4 v[84:87], v161, s[8:9] offset:16\n"
    "global_load_dwordx4 v[88:91], v165, s[8:9]\n"
    "global_load_dwordx4 v[92:95], v165, s[8:9] offset:16\n"
    // ---- xp bank A <- block 0 ----
    LOAD_BANK_A
    ADV_XP
    "s_waitcnt vmcnt(0)\n"
    "s_barrier\n"
    // ---- main loop: 2 blocks (16 steps) per iteration ----
    "1:\n"
    LOAD_BANK_B
    ADV_XP
    "s_waitcnt vmcnt(16)\n"
    STEP_E("v96","0")
    STEP_O("v97","256")
    STEP_E("v98","512")
    STEP_O("v99","768")
    STEP_E("v100","1024")
    STEP_O("v101","1280")
    STEP_E("v102","1536")
    STEP_O("v103","1792")
    ADV_HS
    LOAD_BANK_A
    ADV_XP
    "s_waitcnt vmcnt(16)\n"
    STEP_E("v104","0")
    STEP_O("v105","256")
    STEP_E("v106","512")
    STEP_O("v107","768")
    STEP_E("v108","1024")
    STEP_O("v109","1280")
    STEP_E("v110","1536")
    STEP_O("v111","1792")
    ADV_HS
    "s_sub_u32 s6, s6, 1\n"
    "s_cmp_lg_u32 s6, 0\n"
    "s_cbranch_scc1 1b\n"
    :
    : [xpa]"s"(xpa), [hsp]"s"(hsp), [whh]"s"(whh), [nb2]"s"(nb2),
      [hra]"v"(hra), [hwa]"v"(hwa), [hso]"v"(hso), [xpo]"v"(xpo),
      [wof0]"v"(wof0), [wof1]"v"(wof1), [sv]"v"(sv), [b0]"v"(b0), [b1]"v"(b1),
      [ksc]"v"(ksc), [kml]"v"(kml), [kad]"v"(kad)
    : "memory","scc","vcc",
      "s0","s1","s2","s3","s4","s5","s6","s7","s8","s9","s10","s11","s12","s13",
      "s14","s15","s16","s17",
      "v0","v1","v2","v3","v4","v5","v6","v7","v8","v9","v10","v11","v12","v13","v14","v15",
      "v16","v17","v18","v19","v20","v21","v22","v23","v24","v25","v26","v27","v28","v29","v30","v31",
      "v32","v33","v34","v35","v36","v37","v38","v39","v40","v41","v42","v43","v44","v45","v46","v47",
      "v48","v49","v50","v51","v52","v53","v54","v55","v56","v57","v58","v59","v60","v61","v62","v63",
      "v64","v65","v66","v67","v68","v69","v70","v71","v72","v73","v74","v75","v76","v77","v78","v79",
      "v80","v81","v82","v83","v84","v85","v86","v87","v88","v89","v90","v91","v92","v93","v94","v95",
      "v96","v97","v98","v99","v100","v101","v102","v103","v104","v105","v106","v107","v108","v109","v110","v111",
      "v160","v161","v162","v163","v164","v165");
}

// ---- fallback scan (MODES 1,2) — round-2-verified structure ----------------
template<int MODE>
__global__ __launch_bounds__(256,1) void lstm_scan(
    const float* __restrict__ xp, const float* __restrict__ x,
    const float* __restrict__ W_ih, const float* __restrict__ W_hh,
    const float* __restrict__ b_ih, const float* __restrict__ b_hh,
    const float* __restrict__ W_lin, const float* __restrict__ b_lin,
    const float* __restrict__ W_fin, const float* __restrict__ b_fin,
    float* __restrict__ hs, float* __restrict__ out, int T)
{
  const int tid = threadIdx.x;
  const int w = tid >> 6, l = tid & 63;
  const int gate = l & 3;
  const int u64i = w * 16 + (l >> 2);
  const int row = gate * 64 + u64i;

  float wv[64];
  { const float4* wr = (const float4*)(W_hh + (size_t)row*64);
    #pragma unroll
    for (int k=0;k<16;++k){ float4 q=wr[k]; wv[4*k]=q.x; wv[4*k+1]=q.y; wv[4*k+2]=q.z; wv[4*k+3]=q.w; } }

  const bool isg = (gate == 2);
  const float kscale = isg ? (-2.f*LOG2E) : (-LOG2E);
  const float kmul = isg ? 2.f : 1.f;
  const float kadd = isg ? -1.f : 0.f;
  float c = 0.f;

  __shared__ alignas(16) float hbufs[2][64];
  if (tid < 64){ hbufs[0][tid] = 0.f; hbufs[1][tid] = 0.f; }

  float wih[64]; float bias = 0.f;
  __shared__ alignas(16) float xlds[2][512];
  float px0=0.f, px1=0.f;
  const size_t N = (size_t)T * 64;

  {
    const float4* wr = (const float4*)(W_ih + (size_t)row*64);
    #pragma unroll
    for (int k=0;k<16;++k){ float4 q=wr[k]; wih[4*k]=q.x; wih[4*k+1]=q.y; wih[4*k+2]=q.z; wih[4*k+3]=q.w; }
    bias = b_ih[row] + b_hh[row];
    px0 = x[tid]; px1 = x[(size_t)tid + 256];
    xlds[0][tid] = px0; xlds[0][tid+256] = px1;
    size_t i0 = (size_t)512 + tid, i1 = (size_t)512 + tid + 256;
    px0 = x[i0 < N ? i0 : (N-1)];
    px1 = x[i1 < N ? i1 : (N-1)];
  }

  float wlin[64], blin_l=0.f, wfin_l=0.f, bfin=0.f;
  if (MODE == 2){
    const float4* wr = (const float4*)(W_lin + (size_t)l*64);
    #pragma unroll
    for (int k=0;k<16;++k){ float4 q=wr[k]; wlin[4*k]=q.x; wlin[4*k+1]=q.y; wlin[4*k+2]=q.z; wlin[4*k+3]=q.w; }
    blin_l = b_lin[l]; wfin_l = W_fin[l]; bfin = b_fin[0];
  }

  __syncthreads();

  for (int tb = 0; tb < T; tb += 8){
    {
      const int gi = tb >> 3;
      float* xd = xlds[(gi+1)&1];
      xd[tid] = px0; xd[tid+256] = px1;
      const size_t base = (size_t)(gi+2) * 512;
      size_t i0 = base + tid, i1 = base + tid + 256;
      px0 = x[i0 < N ? i0 : (N-1)];
      px1 = x[i1 < N ? i1 : (N-1)];
    }
    #pragma unroll
    for (int j=0;j<8;++j){
      const int t = tb + j;
      const float4* hbp = (const float4*)hbufs[t&1];
      float a0=0,a1=0,a2=0,a3=0;
      float m0=0,m1=0,m2=0,m3=0;
      #pragma unroll
      for (int k=0;k<16;++k){
        float4 hk = hbp[k];
        a0 = fmaf(wv[4*k+0], hk.x, a0);
        a1 = fmaf(wv[4*k+1], hk.y, a1);
        a2 = fmaf(wv[4*k+2], hk.z, a2);
        a3 = fmaf(wv[4*k+3], hk.w, a3);
        if (MODE == 2){
          m0 = fmaf(wlin[4*k+0], fmaxf(hk.x,0.f), m0);
          m1 = fmaf(wlin[4*k+1], fmaxf(hk.y,0.f), m1);
          m2 = fmaf(wlin[4*k+2], fmaxf(hk.z,0.f), m2);
          m3 = fmaf(wlin[4*k+3], fmaxf(hk.w,0.f), m3);
        }
      }
      float z = (a0+a1)+(a2+a3);
      {
        const float4* xr = (const float4*)&xlds[(tb>>3)&1][j*64];
        float b0=0,b1=0,b2=0,b3=0;
        #pragma unroll
        for (int k=0;k<16;++k){
          float4 q = xr[k];
          b0 = fmaf(wih[4*k+0], q.x, b0);
          b1 = fmaf(wih[4*k+1], q.y, b1);
          b2 = fmaf(wih[4*k+2], q.z, b2);
          b3 = fmaf(wih[4*k+3], q.w, b3);
        }
        z += bias + ((b0+b1)+(b2+b3));
      }
      if (MODE == 2){
        float mid = fmaxf(blin_l + ((m0+m1)+(m2+m3)), 0.f);
        float po = wfin_l * mid;
        if (w == 0){
          po += __shfl_xor(po,1); po += __shfl_xor(po,2); po += __shfl_xor(po,4);
          po += __shfl_xor(po,8); po += __shfl_xor(po,16); po += __shfl_xor(po,32);
          if (l == 0 && t > 0) out[t-1] = po + bfin;
        }
      }
      float e = fast_exp2(z * kscale);
      float sgm = fast_rcp(1.f + e);
      float v = fmaf(sgm, kmul, kadd);
      const float q1 = qperm<0xB1>(v);
      const float q2 = qperm<0x4E>(v);
      const float q3 = qperm<0x1B>(v);
      c = fmaf(q1, c, v * q2);
      const float e2 = fast_exp2((-2.f*LOG2E) * c);
      const float tc = fmaf(fast_rcp(1.f + e2), 2.f, -1.f);
      const float h = q3 * tc;
      if ((l & 3) == 0){
        hbufs[(t&1)^1][u64i] = h;
        if (MODE <= 1) hs[(size_t)t*64 + u64i] = h;
      }
      LDS_BARRIER();
    }
  }
  if (MODE == 2){
    const float4* hbp = (const float4*)hbufs[T&1];
    float m0=0,m1=0,m2=0,m3=0;
    #pragma unroll
    for (int k=0;k<16;++k){
      float4 hk = hbp[k];
      m0 = fmaf(wlin[4*k+0], fmaxf(hk.x,0.f), m0);
      m1 = fmaf(wlin[4*k+1], fmaxf(hk.y,0.f), m1);
      m2 = fmaf(wlin[4*k+2], fmaxf(hk.z,0.f), m2);
      m3 = fmaf(wlin[4*k+3], fmaxf(hk.w,0.f), m3);
    }
    float mid = fmaxf(blin_l + ((m0+m1)+(m2+m3)), 0.f);
    float po = wfin_l * mid;
    if (w == 0){
      po += __shfl_xor(po,1); po += __shfl_xor(po,2); po += __shfl_xor(po,4);
      po += __shfl_xor(po,8); po += __shfl_xor(po,16); po += __shfl_xor(po,32);
      if (l == 0) out[T-1] = po + bfin;
    }
  }
}

__global__ __launch_bounds__(128) void postproc_kernel(
    const float* __restrict__ hs, const float* __restrict__ W_lin,
    const float* __restrict__ b_lin, const float* __restrict__ W_fin,
    const float* __restrict__ b_fin, float* __restrict__ out, int T)
{
  __shared__ alignas(16) float wl[4096];
  __shared__ float ht[128][65];
  __shared__ float sb[64], sw[64];
  const int tid = threadIdx.x;
  #pragma unroll
  for (int i=0;i<32;++i){ int f = tid + i*128; wl[f] = W_lin[f]; }
  if (tid < 64){ sb[tid] = b_lin[tid]; sw[tid] = W_fin[tid]; }
  const size_t t0 = (size_t)blockIdx.x * 128;
  #pragma unroll
  for (int i=0;i<64;++i){ int f = tid + i*128; ht[f>>6][f&63] = hs[t0*64 + f]; }
  __syncthreads();
  float rh[64];
  #pragma unroll
  for (int k=0;k<64;++k) rh[k] = fmaxf(ht[tid][k], 0.f);
  float acc = b_fin[0];
  for (int j=0;j<64;++j){
    const float4* wr = (const float4*)(wl + j*64);
    float m0=sb[j],m1=0,m2=0,m3=0;
    #pragma unroll
    for (int k=0;k<16;++k){
      float4 q = wr[k];
      m0 = fmaf(q.x, rh[4*k+0], m0);
      m1 = fmaf(q.y, rh[4*k+1], m1);
      m2 = fmaf(q.z, rh[4*k+2], m2);
      m3 = fmaf(q.w, rh[4*k+3], m3);
    }
    acc = fmaf(sw[j], fmaxf((m0+m1)+(m2+m3), 0.f), acc);
  }
  out[t0 + tid] = acc;
}

extern "C" void kernel_launch(void* const* d_in, const int* in_sizes, int n_in,
                              void* d_out, int out_size, void* d_ws, size_t ws_size,
                              hipStream_t stream)
{
  const float* x    = (const float*)d_in[0];
  const float* W_ih = (const float*)d_in[1];
  const float* W_hh = (const float*)d_in[2];
  const float* b_ih = (const float*)d_in[3];
  const float* b_hh = (const float*)d_in[4];
  const float* W_lin= (const float*)d_in[5];
  const float* b_lin= (const float*)d_in[6];
  const float* W_fin= (const float*)d_in[7];
  const float* b_fin= (const float*)d_in[8];
  float* out = (float*)d_out;
  const int T = in_sizes[0] / 64;
  const size_t xp_bytes = (size_t)T * 256 * sizeof(float);
  const size_t hs_bytes = (size_t)T * 64 * sizeof(float);

  if (ws_size >= xp_bytes + hs_bytes && (T % 16) == 0 && T >= 32){
    float* xp = (float*)d_ws;
    float* hs = (float*)((char*)d_ws + xp_bytes);
    xproj_kernel<<<T/128, 256, 0, stream>>>(x, W_ih, b_ih, b_hh, xp, T);
    lstm_scan_asm<<<1, 256, 0, stream>>>(xp, W_hh, hs, T);
    postproc_kernel<<<T/128, 128, 0, stream>>>(hs, W_lin, b_lin, W_fin, b_fin, out, T);
  } else if (ws_size >= hs_bytes){
    float* hs = (float*)d_ws;
    lstm_scan<1><<<1, 256, 0, stream>>>(nullptr, x, W_ih, W_hh, b_ih, b_hh,
                                        W_lin, b_lin, W_fin, b_fin, hs, out, T);
    postproc_kernel<<<T/128, 128, 0, stream>>>(hs, W_lin, b_lin, W_fin, b_fin, out, T);
  } else {
    lstm_scan<2><<<1, 256, 0, stream>>>(nullptr, x, W_ih, W_hh, b_ih, b_hh,
                                        W_lin, b_lin, W_fin, b_fin, nullptr, out, T);
  }
}